// Round 2
// baseline (315.852 us; speedup 1.0000x reference)
//
#include <hip/hip_runtime.h>

// Mamba block fused pipeline, MI355X gfx950.
// B=1, L=2048, D_MODEL=1024, D_INNER=2048, D_CONV=4, DT_RANK=64, D_STATE=16.
//
// R1 changes: scan kernels split the 16 states 4-way across lanes
// (4 lanes per (channel,chunk), shfl_xor reduction for y) -> 4x waves/SIMD,
// fixing the 9% occupancy / 26% VALUBusy latency bound seen in rocprof.
// G3 split-K raised 4 -> 16 (64 -> 256 blocks).

#define L_SEQ 2048
#define DMODEL 1024
#define DINNER 2048
#define NSTATE 16
#define DTRANK 64
#define NPROJ_PAD 128
#define NCHUNK 32
#define TCH 64  // L_SEQ / NCHUNK

typedef __attribute__((ext_vector_type(8))) short short8;
typedef __attribute__((ext_vector_type(4))) float f32x4;

__device__ __forceinline__ unsigned short f2bf(float f) {
  unsigned int u = __float_as_uint(f);
  u += 0x7FFFu + ((u >> 16) & 1u);  // round-to-nearest-even
  return (unsigned short)(u >> 16);
}

__device__ __forceinline__ void gload16(const void* g, void* l) {
  // async global->LDS, 16B per lane; LDS dest = base + lane*16
  __builtin_amdgcn_global_load_lds((const __attribute__((address_space(1))) void*)g,
                                   (__attribute__((address_space(3))) void*)l, 16, 0, 0);
}

// ---------------- elementwise / prep kernels ----------------

__global__ void cast_bf16_kernel(const float* __restrict__ in, unsigned short* __restrict__ out,
                                 int n) {
  int id = blockIdx.x * 256 + threadIdx.x;
  if (id < n) out[id] = f2bf(in[id]);
}

// dt slice (cols 0..63 of dbc row stride 128) -> contiguous bf16 (2048x64)
__global__ void cast_dt_kernel(const float* __restrict__ dbc, unsigned short* __restrict__ dtb) {
  int id = blockIdx.x * 256 + threadIdx.x;  // 2048*64
  int t = id >> 6, k = id & 63;
  dtb[id] = f2bf(dbc[t * NPROJ_PAD + k]);
}

// in (R x C fp32) -> out (C x R bf16)
__global__ void transpose_cast_kernel(const float* __restrict__ in,
                                      unsigned short* __restrict__ out, int R, int C) {
  __shared__ float tile[32][33];
  const int c0 = blockIdx.x * 32, r0 = blockIdx.y * 32;
  const int tx = threadIdx.x, ty = threadIdx.y;  // block (32,8)
  for (int y = ty; y < 32; y += 8) tile[y][tx] = in[(size_t)(r0 + y) * C + c0 + tx];
  __syncthreads();
  for (int y = ty; y < 32; y += 8) out[(size_t)(c0 + y) * R + r0 + tx] = f2bf(tile[tx][y]);
}

// depthwise causal conv (4 taps) + silu; u fp32 for scan, bf16 for GEMM3
__global__ void conv_silu_kernel(const float* __restrict__ xres, const float* __restrict__ cw,
                                 const float* __restrict__ cb, float* __restrict__ u,
                                 unsigned short* __restrict__ ub) {
  const int id = blockIdx.x * 256 + threadIdx.x;  // over 2048*2048
  const int t = id >> 11;
  const int d = id & (DINNER - 1);
  float acc = cb[d];
#pragma unroll
  for (int j = 0; j < 4; j++) {
    int tt = t - 3 + j;
    if (tt >= 0) acc += xres[(size_t)tt * (2 * DINNER) + d] * cw[j * DINNER + d];
  }
  float s = acc / (1.f + __expf(-acc));  // silu
  u[id] = s;
  ub[id] = f2bf(s);
}

// ---------------- bf16 MFMA GEMM: C[M,N] = A[M,K] @ Bt[N,K]^T ----------------
// 128x128 tile, BK=32, 4 waves each 64x64 of 16x16x32 MFMA frags.
// EPI: 0 = store acc+bias (bias may be null), 1 = store softplus(acc+bias),
//      2 = atomicAdd(C, acc) for split-K (grid.z = K/KS splits).
template <int EPI>
__global__ void gemm_bf16_128(const unsigned short* __restrict__ A,
                              const unsigned short* __restrict__ Bt, float* __restrict__ C,
                              const float* __restrict__ bias, int M, int N, int K, int KS) {
  __shared__ __align__(16) unsigned short lA[128 * 32];
  __shared__ __align__(16) unsigned short lB[128 * 32];
  const int tid = threadIdx.x;
  const int w = tid >> 6;
  const int lane = tid & 63;
  const int m0 = blockIdx.x * 128;
  const int n0 = blockIdx.y * 128;
  const int kbase = blockIdx.z * KS;
  const int lr = lane >> 2;       // row within 16-row group the lane stages
  const int lc = (lane & 3) * 8;  // k-offset (elements) the lane stages
  const int wm = (w & 1) * 64;
  const int wn = (w >> 1) * 64;
  const int ml = lane & 15;
  const int quad = lane >> 4;

  f32x4 acc[4][4];
#pragma unroll
  for (int i = 0; i < 4; i++)
#pragma unroll
    for (int j = 0; j < 4; j++) acc[i][j] = (f32x4){0.f, 0.f, 0.f, 0.f};

  const unsigned short* Ag = A + (size_t)m0 * K + kbase;
  const unsigned short* Bg = Bt + (size_t)n0 * K + kbase;

  for (int kk = 0; kk < KS; kk += 32) {
    // stage A,B tiles (128x32 bf16 each, rows contiguous 64B)
    gload16(Ag + (size_t)(w * 16 + lr) * K + kk + lc, &lA[(w * 16) * 32]);
    gload16(Ag + (size_t)(64 + w * 16 + lr) * K + kk + lc, &lA[(64 + w * 16) * 32]);
    gload16(Bg + (size_t)(w * 16 + lr) * K + kk + lc, &lB[(w * 16) * 32]);
    gload16(Bg + (size_t)(64 + w * 16 + lr) * K + kk + lc, &lB[(64 + w * 16) * 32]);
    __syncthreads();

    short8 af[4], bfr[4];
#pragma unroll
    for (int i = 0; i < 4; i++)
      af[i] = *(const short8*)&lA[(wm + i * 16 + ml) * 32 + quad * 8];
#pragma unroll
    for (int j = 0; j < 4; j++)
      bfr[j] = *(const short8*)&lB[(wn + j * 16 + ml) * 32 + quad * 8];
#pragma unroll
    for (int i = 0; i < 4; i++)
#pragma unroll
      for (int j = 0; j < 4; j++)
        acc[i][j] = __builtin_amdgcn_mfma_f32_16x16x32_bf16(af[i], bfr[j], acc[i][j], 0, 0, 0);
    __syncthreads();
  }

  // epilogue: C/D layout col = lane&15, row = quad*4 + r
#pragma unroll
  for (int i = 0; i < 4; i++) {
#pragma unroll
    for (int j = 0; j < 4; j++) {
      const int col = n0 + wn + j * 16 + ml;
      float bv = 0.f;
      if (EPI != 2 && bias != nullptr) bv = bias[col];
#pragma unroll
      for (int r = 0; r < 4; r++) {
        const int row = m0 + wm + i * 16 + quad * 4 + r;
        float v = acc[i][j][r];
        if (EPI == 2) {
          atomicAdd(&C[(size_t)row * N + col], v);
        } else {
          v += bv;
          if (EPI == 1) v = (v > 15.f) ? v : __logf(1.f + __expf(v));
          C[(size_t)row * N + col] = v;
        }
      }
    }
  }
}

// ---------------- selective scan (chunked 2-pass, 4-way state split) ----------------
// 4 lanes per (channel d, chunk c), 4 states each.
// Lane mapping within a wave: d_sub = lane&15, state group sgrp = lane>>4.
// Block = 256 threads = 4 waves; each wave covers 16 channels; block covers 64.

__global__ void scan1_kernel(const float* __restrict__ delta, const float* __restrict__ u,
                             const float* __restrict__ dbc, const float* __restrict__ A_log,
                             float* __restrict__ P, float* __restrict__ Hz) {
  __shared__ __align__(16) float Bs[TCH][NSTATE];
  const int tid = threadIdx.x;
  const int wv = tid >> 6;
  const int lane = tid & 63;
  const int sgrp = lane >> 4;                          // 0..3
  const int d = blockIdx.x * 64 + wv * 16 + (lane & 15);
  const int c = blockIdx.y;
  for (int idx = tid; idx < TCH * NSTATE; idx += 256) {
    int t = idx >> 4, n = idx & 15;
    Bs[t][n] = dbc[(size_t)(c * TCH + t) * NPROJ_PAD + DTRANK + n];
  }
  f32x4 al = *(const f32x4*)&A_log[d * 16 + sgrp * 4];
  float Ad[4], h[4], p[4];
#pragma unroll
  for (int n = 0; n < 4; n++) {
    Ad[n] = -__expf(al[n]);
    h[n] = 0.f;
    p[n] = 1.f;
  }
  __syncthreads();
  for (int t = 0; t < TCH; t++) {
    const int tt = c * TCH + t;
    float dl = delta[(size_t)tt * DINNER + d];
    float uu = u[(size_t)tt * DINNER + d];
    float du = dl * uu;
    f32x4 bt = *(const f32x4*)&Bs[t][sgrp * 4];
#pragma unroll
    for (int n = 0; n < 4; n++) {
      float dA = __expf(dl * Ad[n]);
      p[n] *= dA;
      h[n] = dA * h[n] + du * bt[n];
    }
  }
#pragma unroll
  for (int n = 0; n < 4; n++) {
    P[(size_t)(c * 16 + sgrp * 4 + n) * DINNER + d] = p[n];
    Hz[(size_t)(c * 16 + sgrp * 4 + n) * DINNER + d] = h[n];
  }
}

__global__ void scan_carry_kernel(const float* __restrict__ P, const float* __restrict__ Hz,
                                  float* __restrict__ H0) {
  const int id = blockIdx.x * 256 + threadIdx.x;  // 16*2048 (n,d) pairs
  float h = 0.f;
#pragma unroll 4
  for (int c = 0; c < NCHUNK; c++) {
    H0[c * (NSTATE * DINNER) + id] = h;
    h = P[c * (NSTATE * DINNER) + id] * h + Hz[c * (NSTATE * DINNER) + id];
  }
}

__global__ void scan2_kernel(const float* __restrict__ delta, const float* __restrict__ u,
                             const float* __restrict__ dbc, const float* __restrict__ A_log,
                             const float* __restrict__ Dv, const float* __restrict__ xres,
                             const float* __restrict__ H0, unsigned short* __restrict__ ygb) {
  __shared__ __align__(16) float Bs[TCH][NSTATE];
  __shared__ __align__(16) float Cs[TCH][NSTATE];
  const int tid = threadIdx.x;
  const int wv = tid >> 6;
  const int lane = tid & 63;
  const int sgrp = lane >> 4;
  const int d = blockIdx.x * 64 + wv * 16 + (lane & 15);
  const int c = blockIdx.y;
  for (int idx = tid; idx < TCH * 2 * NSTATE; idx += 256) {
    int t = idx >> 5, q = idx & 31;
    float v = dbc[(size_t)(c * TCH + t) * NPROJ_PAD + DTRANK + q];
    if (q < 16) Bs[t][q] = v;
    else Cs[t][q - 16] = v;
  }
  f32x4 al = *(const f32x4*)&A_log[d * 16 + sgrp * 4];
  float Ad[4], h[4];
#pragma unroll
  for (int n = 0; n < 4; n++) {
    Ad[n] = -__expf(al[n]);
    h[n] = H0[(size_t)(c * 16 + sgrp * 4 + n) * DINNER + d];
  }
  const float Dd = Dv[d];
  __syncthreads();
  for (int t = 0; t < TCH; t++) {
    const int tt = c * TCH + t;
    float dl = delta[(size_t)tt * DINNER + d];
    float uu = u[(size_t)tt * DINNER + d];
    float du = dl * uu;
    f32x4 bt = *(const f32x4*)&Bs[t][sgrp * 4];
    f32x4 ct = *(const f32x4*)&Cs[t][sgrp * 4];
    float y = 0.f;
#pragma unroll
    for (int n = 0; n < 4; n++) {
      float dA = __expf(dl * Ad[n]);
      h[n] = dA * h[n] + du * bt[n];
      y += h[n] * ct[n];
    }
    // reduce y across the 4 state-group lanes (lane ^16, ^32)
    y += __shfl_xor(y, 16, 64);
    y += __shfl_xor(y, 32, 64);
    float r = xres[(size_t)tt * (2 * DINNER) + DINNER + d];
    float sil = r / (1.f + __expf(-r));
    float yg = (y + uu * Dd) * sil;
    if (sgrp == 0) ygb[(size_t)tt * DINNER + d] = f2bf(yg);
  }
}

// ---------------- launch ----------------

extern "C" void kernel_launch(void* const* d_in, const int* in_sizes, int n_in, void* d_out,
                              int out_size, void* d_ws, size_t ws_size, hipStream_t stream) {
  const float* x = (const float*)d_in[0];
  const float* in_proj_w = (const float*)d_in[1];
  const float* in_proj_b = (const float*)d_in[2];
  const float* conv_w = (const float*)d_in[3];
  const float* conv_b = (const float*)d_in[4];
  const float* x_proj_w = (const float*)d_in[5];
  const float* dt_proj_w = (const float*)d_in[6];
  const float* dt_proj_b = (const float*)d_in[7];
  const float* A_log = (const float*)d_in[8];
  const float* Dvec = (const float*)d_in[9];
  const float* out_proj_w = (const float*)d_in[10];
  const float* out_proj_b = (const float*)d_in[11];
  float* out = (float*)d_out;
  char* ws = (char*)d_ws;

  // workspace layout (bytes), all 256-aligned; total ~115 MiB
  const size_t XB = 0;                       // 2048x1024 bf16        4 MiB
  const size_t W1T = XB + 4194304;           // 4096x1024 bf16        8 MiB
  const size_t XRES = W1T + 8388608;         // 2048x4096 fp32       32 MiB
  const size_t U = XRES + 33554432;          // 2048x2048 fp32       16 MiB
  const size_t UB = U + 16777216;            // 2048x2048 bf16        8 MiB
  const size_t W3T = UB + 8388608;           // 128x2048 bf16       0.5 MiB
  const size_t DBC = W3T + 524288;           // 2048x128 fp32         1 MiB
  const size_t DTB = DBC + 1048576;          // 2048x64 bf16       0.25 MiB
  const size_t W4T = DTB + 262144;           // 2048x64 bf16       0.25 MiB
  const size_t DELTA = W4T + 262144;         // 2048x2048 fp32       16 MiB
  const size_t PBUF = DELTA + 16777216;      // 32x16x2048 fp32       4 MiB
  const size_t HZB = PBUF + 4194304;         //                       4 MiB
  const size_t H0B = HZB + 4194304;          //                       4 MiB
  const size_t YGB = H0B + 4194304;          // 2048x2048 bf16        8 MiB
  const size_t W5T = YGB + 8388608;          // 1024x2048 bf16        4 MiB
  (void)ws_size; (void)in_sizes; (void)n_in; (void)out_size;

  // zero pad rows of w3t and the split-K accumulator
  hipMemsetAsync(ws + W3T, 0, NPROJ_PAD * DINNER * 2, stream);
  hipMemsetAsync(ws + DBC, 0, (size_t)L_SEQ * NPROJ_PAD * 4, stream);

  // prep casts
  cast_bf16_kernel<<<(L_SEQ * DMODEL) / 256, 256, 0, stream>>>(x, (unsigned short*)(ws + XB),
                                                               L_SEQ * DMODEL);
  transpose_cast_kernel<<<dim3(4096 / 32, 1024 / 32), dim3(32, 8), 0, stream>>>(
      in_proj_w, (unsigned short*)(ws + W1T), 1024, 4096);
  transpose_cast_kernel<<<dim3(96 / 32, 2048 / 32), dim3(32, 8), 0, stream>>>(
      x_proj_w, (unsigned short*)(ws + W3T), 2048, 96);
  transpose_cast_kernel<<<dim3(2048 / 32, 64 / 32), dim3(32, 8), 0, stream>>>(
      dt_proj_w, (unsigned short*)(ws + W4T), 64, 2048);
  transpose_cast_kernel<<<dim3(1024 / 32, 2048 / 32), dim3(32, 8), 0, stream>>>(
      out_proj_w, (unsigned short*)(ws + W5T), 2048, 1024);

  // G1: xres = x @ in_proj_w + b   (M=2048,N=4096,K=1024)
  gemm_bf16_128<0><<<dim3(16, 32, 1), 256, 0, stream>>>(
      (const unsigned short*)(ws + XB), (const unsigned short*)(ws + W1T), (float*)(ws + XRES),
      in_proj_b, 2048, 4096, 1024, 1024);

  // conv + silu
  conv_silu_kernel<<<(L_SEQ * DINNER) / 256, 256, 0, stream>>>(
      (const float*)(ws + XRES), conv_w, conv_b, (float*)(ws + U), (unsigned short*)(ws + UB));

  // G3: dbc += u @ x_proj_w  (M=2048,N=128,K=2048, split-K=16 w/ atomics)
  gemm_bf16_128<2><<<dim3(16, 1, 16), 256, 0, stream>>>(
      (const unsigned short*)(ws + UB), (const unsigned short*)(ws + W3T), (float*)(ws + DBC),
      nullptr, 2048, NPROJ_PAD, 2048, 128);

  cast_dt_kernel<<<(L_SEQ * DTRANK) / 256, 256, 0, stream>>>((const float*)(ws + DBC),
                                                             (unsigned short*)(ws + DTB));

  // G5: delta = softplus(dt @ dt_proj_w + b)  (M=2048,N=2048,K=64)
  gemm_bf16_128<1><<<dim3(16, 16, 1), 256, 0, stream>>>(
      (const unsigned short*)(ws + DTB), (const unsigned short*)(ws + W4T), (float*)(ws + DELTA),
      dt_proj_b, 2048, 2048, 64, 64);

  // selective scan (4-way state split: 32x32=1024 blocks)
  scan1_kernel<<<dim3(DINNER / 64, NCHUNK), 256, 0, stream>>>(
      (const float*)(ws + DELTA), (const float*)(ws + U), (const float*)(ws + DBC), A_log,
      (float*)(ws + PBUF), (float*)(ws + HZB));
  scan_carry_kernel<<<(NSTATE * DINNER) / 256, 256, 0, stream>>>(
      (const float*)(ws + PBUF), (const float*)(ws + HZB), (float*)(ws + H0B));
  scan2_kernel<<<dim3(DINNER / 64, NCHUNK), 256, 0, stream>>>(
      (const float*)(ws + DELTA), (const float*)(ws + U), (const float*)(ws + DBC), A_log, Dvec,
      (const float*)(ws + XRES), (const float*)(ws + H0B), (unsigned short*)(ws + YGB));

  // G2: out = yg @ out_proj_w + b  (M=2048,N=1024,K=2048)
  gemm_bf16_128<0><<<dim3(16, 8, 1), 256, 0, stream>>>(
      (const unsigned short*)(ws + YGB), (const unsigned short*)(ws + W5T), out, out_proj_b, 2048,
      1024, 2048, 2048);
}

// Round 3
// 289.045 us; speedup vs baseline: 1.0927x; 1.0927x over previous
//
#include <hip/hip_runtime.h>

// Mamba block fused pipeline, MI355X gfx950.
// B=1, L=2048, D_MODEL=1024, D_INNER=2048, D_CONV=4, DT_RANK=64, D_STATE=16.
//
// R2 changes: scan reverted to thread=channel mapping (R1 lane-split regressed:
// duplicated scalar work + 16-lane coalescing). Parallelism now comes from
// chunk count: NCHUNK 32 -> 128 (TCH=16, compile-time, fully unrolled t-loop so
// all chunk loads issue before the exp/fma chain -> one latency per chunk, not
// per timestep). Carry buffers tiered on ws_size (128/64/32 chunks).

#define L_SEQ 2048
#define DMODEL 1024
#define DINNER 2048
#define NSTATE 16
#define DTRANK 64
#define NPROJ_PAD 128

typedef __attribute__((ext_vector_type(8))) short short8;
typedef __attribute__((ext_vector_type(4))) float f32x4;

__device__ __forceinline__ unsigned short f2bf(float f) {
  unsigned int u = __float_as_uint(f);
  u += 0x7FFFu + ((u >> 16) & 1u);  // round-to-nearest-even
  return (unsigned short)(u >> 16);
}

__device__ __forceinline__ void gload16(const void* g, void* l) {
  // async global->LDS, 16B per lane; LDS dest = base + lane*16
  __builtin_amdgcn_global_load_lds((const __attribute__((address_space(1))) void*)g,
                                   (__attribute__((address_space(3))) void*)l, 16, 0, 0);
}

// ---------------- elementwise / prep kernels ----------------

__global__ void cast_bf16_kernel(const float* __restrict__ in, unsigned short* __restrict__ out,
                                 int n) {
  int id = blockIdx.x * 256 + threadIdx.x;
  if (id < n) out[id] = f2bf(in[id]);
}

// dt slice (cols 0..63 of dbc row stride 128) -> contiguous bf16 (2048x64)
__global__ void cast_dt_kernel(const float* __restrict__ dbc, unsigned short* __restrict__ dtb) {
  int id = blockIdx.x * 256 + threadIdx.x;  // 2048*64
  int t = id >> 6, k = id & 63;
  dtb[id] = f2bf(dbc[t * NPROJ_PAD + k]);
}

// in (R x C fp32) -> out (C x R bf16)
__global__ void transpose_cast_kernel(const float* __restrict__ in,
                                      unsigned short* __restrict__ out, int R, int C) {
  __shared__ float tile[32][33];
  const int c0 = blockIdx.x * 32, r0 = blockIdx.y * 32;
  const int tx = threadIdx.x, ty = threadIdx.y;  // block (32,8)
  for (int y = ty; y < 32; y += 8) tile[y][tx] = in[(size_t)(r0 + y) * C + c0 + tx];
  __syncthreads();
  for (int y = ty; y < 32; y += 8) out[(size_t)(c0 + y) * R + r0 + tx] = f2bf(tile[tx][y]);
}

// depthwise causal conv (4 taps) + silu; u fp32 for scan, bf16 for GEMM3
__global__ void conv_silu_kernel(const float* __restrict__ xres, const float* __restrict__ cw,
                                 const float* __restrict__ cb, float* __restrict__ u,
                                 unsigned short* __restrict__ ub) {
  const int id = blockIdx.x * 256 + threadIdx.x;  // over 2048*2048
  const int t = id >> 11;
  const int d = id & (DINNER - 1);
  float acc = cb[d];
#pragma unroll
  for (int j = 0; j < 4; j++) {
    int tt = t - 3 + j;
    if (tt >= 0) acc += xres[(size_t)tt * (2 * DINNER) + d] * cw[j * DINNER + d];
  }
  float s = acc / (1.f + __expf(-acc));  // silu
  u[id] = s;
  ub[id] = f2bf(s);
}

// ---------------- bf16 MFMA GEMM: C[M,N] = A[M,K] @ Bt[N,K]^T ----------------
// 128x128 tile, BK=32, 4 waves each 64x64 of 16x16x32 MFMA frags.
// EPI: 0 = store acc+bias (bias may be null), 1 = store softplus(acc+bias),
//      2 = atomicAdd(C, acc) for split-K (grid.z = K/KS splits).
template <int EPI>
__global__ void gemm_bf16_128(const unsigned short* __restrict__ A,
                              const unsigned short* __restrict__ Bt, float* __restrict__ C,
                              const float* __restrict__ bias, int M, int N, int K, int KS) {
  __shared__ __align__(16) unsigned short lA[128 * 32];
  __shared__ __align__(16) unsigned short lB[128 * 32];
  const int tid = threadIdx.x;
  const int w = tid >> 6;
  const int lane = tid & 63;
  const int m0 = blockIdx.x * 128;
  const int n0 = blockIdx.y * 128;
  const int kbase = blockIdx.z * KS;
  const int lr = lane >> 2;       // row within 16-row group the lane stages
  const int lc = (lane & 3) * 8;  // k-offset (elements) the lane stages
  const int wm = (w & 1) * 64;
  const int wn = (w >> 1) * 64;
  const int ml = lane & 15;
  const int quad = lane >> 4;

  f32x4 acc[4][4];
#pragma unroll
  for (int i = 0; i < 4; i++)
#pragma unroll
    for (int j = 0; j < 4; j++) acc[i][j] = (f32x4){0.f, 0.f, 0.f, 0.f};

  const unsigned short* Ag = A + (size_t)m0 * K + kbase;
  const unsigned short* Bg = Bt + (size_t)n0 * K + kbase;

  for (int kk = 0; kk < KS; kk += 32) {
    // stage A,B tiles (128x32 bf16 each, rows contiguous 64B)
    gload16(Ag + (size_t)(w * 16 + lr) * K + kk + lc, &lA[(w * 16) * 32]);
    gload16(Ag + (size_t)(64 + w * 16 + lr) * K + kk + lc, &lA[(64 + w * 16) * 32]);
    gload16(Bg + (size_t)(w * 16 + lr) * K + kk + lc, &lB[(w * 16) * 32]);
    gload16(Bg + (size_t)(64 + w * 16 + lr) * K + kk + lc, &lB[(64 + w * 16) * 32]);
    __syncthreads();

    short8 af[4], bfr[4];
#pragma unroll
    for (int i = 0; i < 4; i++)
      af[i] = *(const short8*)&lA[(wm + i * 16 + ml) * 32 + quad * 8];
#pragma unroll
    for (int j = 0; j < 4; j++)
      bfr[j] = *(const short8*)&lB[(wn + j * 16 + ml) * 32 + quad * 8];
#pragma unroll
    for (int i = 0; i < 4; i++)
#pragma unroll
      for (int j = 0; j < 4; j++)
        acc[i][j] = __builtin_amdgcn_mfma_f32_16x16x32_bf16(af[i], bfr[j], acc[i][j], 0, 0, 0);
    __syncthreads();
  }

  // epilogue: C/D layout col = lane&15, row = quad*4 + r
#pragma unroll
  for (int i = 0; i < 4; i++) {
#pragma unroll
    for (int j = 0; j < 4; j++) {
      const int col = n0 + wn + j * 16 + ml;
      float bv = 0.f;
      if (EPI != 2 && bias != nullptr) bv = bias[col];
#pragma unroll
      for (int r = 0; r < 4; r++) {
        const int row = m0 + wm + i * 16 + quad * 4 + r;
        float v = acc[i][j][r];
        if (EPI == 2) {
          atomicAdd(&C[(size_t)row * N + col], v);
        } else {
          v += bv;
          if (EPI == 1) v = (v > 15.f) ? v : __logf(1.f + __expf(v));
          C[(size_t)row * N + col] = v;
        }
      }
    }
  }
}

// ---------------- selective scan (chunked 2-pass) ----------------
// Thread = one channel d within one chunk; 16 states in registers.
// TCH_T compile-time so the t-loop fully unrolls: all chunk loads issue ahead
// of the exp/fma chain (one global latency per chunk, not per timestep).

template <int TCH_T>
__global__ void scan1_kernel(const float* __restrict__ delta, const float* __restrict__ u,
                             const float* __restrict__ dbc, const float* __restrict__ A_log,
                             float* __restrict__ P, float* __restrict__ Hz) {
  __shared__ float Bs[TCH_T][NSTATE];
  const int d = blockIdx.x * 256 + threadIdx.x;
  const int c = blockIdx.y;
  for (int idx = threadIdx.x; idx < TCH_T * NSTATE; idx += 256) {
    int t = idx >> 4, n = idx & 15;
    Bs[t][n] = dbc[(size_t)(c * TCH_T + t) * NPROJ_PAD + DTRANK + n];
  }
  float Ad[16], h[16], p[16];
#pragma unroll
  for (int n = 0; n < 16; n++) {
    Ad[n] = -__expf(A_log[d * 16 + n]);
    h[n] = 0.f;
    p[n] = 1.f;
  }
  __syncthreads();
#pragma unroll
  for (int t = 0; t < TCH_T; t++) {
    const int tt = c * TCH_T + t;
    float dl = delta[(size_t)tt * DINNER + d];
    float uu = u[(size_t)tt * DINNER + d];
    float du = dl * uu;
#pragma unroll
    for (int n = 0; n < 16; n++) {
      float dA = __expf(dl * Ad[n]);
      p[n] *= dA;
      h[n] = dA * h[n] + du * Bs[t][n];
    }
  }
#pragma unroll
  for (int n = 0; n < 16; n++) {
    P[(size_t)(c * 16 + n) * DINNER + d] = p[n];
    Hz[(size_t)(c * 16 + n) * DINNER + d] = h[n];
  }
}

__global__ void scan_carry_kernel(const float* __restrict__ P, const float* __restrict__ Hz,
                                  float* __restrict__ H0, int nchunk) {
  const int id = blockIdx.x * 256 + threadIdx.x;  // 16*2048 (n,d) pairs
  float h = 0.f;
#pragma unroll 8
  for (int c = 0; c < nchunk; c++) {
    H0[c * (NSTATE * DINNER) + id] = h;
    h = P[c * (NSTATE * DINNER) + id] * h + Hz[c * (NSTATE * DINNER) + id];
  }
}

template <int TCH_T>
__global__ void scan2_kernel(const float* __restrict__ delta, const float* __restrict__ u,
                             const float* __restrict__ dbc, const float* __restrict__ A_log,
                             const float* __restrict__ Dv, const float* __restrict__ xres,
                             const float* __restrict__ H0, unsigned short* __restrict__ ygb) {
  __shared__ float Bs[TCH_T][NSTATE];
  __shared__ float Cs[TCH_T][NSTATE];
  const int d = blockIdx.x * 256 + threadIdx.x;
  const int c = blockIdx.y;
  for (int idx = threadIdx.x; idx < TCH_T * 2 * NSTATE; idx += 256) {
    int t = idx >> 5, q = idx & 31;
    float v = dbc[(size_t)(c * TCH_T + t) * NPROJ_PAD + DTRANK + q];
    if (q < 16) Bs[t][q] = v;
    else Cs[t][q - 16] = v;
  }
  float Ad[16], h[16];
#pragma unroll
  for (int n = 0; n < 16; n++) {
    Ad[n] = -__expf(A_log[d * 16 + n]);
    h[n] = H0[(size_t)(c * 16 + n) * DINNER + d];
  }
  const float Dd = Dv[d];
  __syncthreads();
#pragma unroll
  for (int t = 0; t < TCH_T; t++) {
    const int tt = c * TCH_T + t;
    float dl = delta[(size_t)tt * DINNER + d];
    float uu = u[(size_t)tt * DINNER + d];
    float r = xres[(size_t)tt * (2 * DINNER) + DINNER + d];
    float du = dl * uu;
    float y0 = 0.f, y1 = 0.f;
#pragma unroll
    for (int n = 0; n < 16; n++) {
      float dA = __expf(dl * Ad[n]);
      h[n] = dA * h[n] + du * Bs[t][n];
      if (n & 1) y1 += h[n] * Cs[t][n];
      else y0 += h[n] * Cs[t][n];
    }
    float sil = r / (1.f + __expf(-r));
    float yg = (y0 + y1 + uu * Dd) * sil;
    ygb[(size_t)tt * DINNER + d] = f2bf(yg);
  }
}

// ---------------- launch ----------------

extern "C" void kernel_launch(void* const* d_in, const int* in_sizes, int n_in, void* d_out,
                              int out_size, void* d_ws, size_t ws_size, hipStream_t stream) {
  const float* x = (const float*)d_in[0];
  const float* in_proj_w = (const float*)d_in[1];
  const float* in_proj_b = (const float*)d_in[2];
  const float* conv_w = (const float*)d_in[3];
  const float* conv_b = (const float*)d_in[4];
  const float* x_proj_w = (const float*)d_in[5];
  const float* dt_proj_w = (const float*)d_in[6];
  const float* dt_proj_b = (const float*)d_in[7];
  const float* A_log = (const float*)d_in[8];
  const float* Dvec = (const float*)d_in[9];
  const float* out_proj_w = (const float*)d_in[10];
  const float* out_proj_b = (const float*)d_in[11];
  float* out = (float*)d_out;
  char* ws = (char*)d_ws;

  // workspace layout (bytes), all 256-aligned
  const size_t MB = 1048576;
  const size_t XB = 0;                 // 2048x1024 bf16   4 MiB
  const size_t W1T = 4 * MB;           // 4096x1024 bf16   8 MiB
  const size_t XRES = 12 * MB;         // 2048x4096 fp32  32 MiB
  const size_t U = 44 * MB;            // 2048x2048 fp32  16 MiB
  const size_t UB = 60 * MB;           // 2048x2048 bf16   8 MiB
  const size_t W3T = 68 * MB;          // 128x2048 bf16  0.5 MiB
  const size_t DBC = W3T + 524288;     // 2048x128 fp32    1 MiB
  const size_t DTB = DBC + MB;         // 2048x64 bf16  0.25 MiB
  const size_t W4T = DTB + 262144;     // 2048x64 bf16  0.25 MiB
  const size_t DELTA = 70 * MB;        // 2048x2048 fp32  16 MiB
  const size_t YGB = 86 * MB;          // 2048x2048 bf16   8 MiB
  const size_t W5T = 94 * MB;          // 1024x2048 bf16   4 MiB
  const size_t PBUF = 98 * MB;         // [nch x 16 x 2048] fp32
  (void)in_sizes; (void)n_in; (void)out_size;

  // tier chunk count on available workspace: need PBUF + 3*PB bytes
  // PB(TCH) = (2048/TCH)*16*2048*4
  int tch = 64;
  if (ws_size >= PBUF + 3 * (size_t)(128 * NSTATE * DINNER) * 4) tch = 16;       // 146 MiB
  else if (ws_size >= PBUF + 3 * (size_t)(64 * NSTATE * DINNER) * 4) tch = 32;   // 122 MiB
  const int nch = L_SEQ / tch;
  const size_t PB = (size_t)nch * NSTATE * DINNER * 4;
  const size_t HZB = PBUF + PB;
  const size_t H0B = PBUF + 2 * PB;

  // zero pad rows of w3t and the split-K accumulator
  hipMemsetAsync(ws + W3T, 0, NPROJ_PAD * DINNER * 2, stream);
  hipMemsetAsync(ws + DBC, 0, (size_t)L_SEQ * NPROJ_PAD * 4, stream);

  // prep casts
  cast_bf16_kernel<<<(L_SEQ * DMODEL) / 256, 256, 0, stream>>>(x, (unsigned short*)(ws + XB),
                                                               L_SEQ * DMODEL);
  transpose_cast_kernel<<<dim3(4096 / 32, 1024 / 32), dim3(32, 8), 0, stream>>>(
      in_proj_w, (unsigned short*)(ws + W1T), 1024, 4096);
  transpose_cast_kernel<<<dim3(96 / 32, 2048 / 32), dim3(32, 8), 0, stream>>>(
      x_proj_w, (unsigned short*)(ws + W3T), 2048, 96);
  transpose_cast_kernel<<<dim3(2048 / 32, 64 / 32), dim3(32, 8), 0, stream>>>(
      dt_proj_w, (unsigned short*)(ws + W4T), 64, 2048);
  transpose_cast_kernel<<<dim3(1024 / 32, 2048 / 32), dim3(32, 8), 0, stream>>>(
      out_proj_w, (unsigned short*)(ws + W5T), 2048, 1024);

  // G1: xres = x @ in_proj_w + b   (M=2048,N=4096,K=1024)
  gemm_bf16_128<0><<<dim3(16, 32, 1), 256, 0, stream>>>(
      (const unsigned short*)(ws + XB), (const unsigned short*)(ws + W1T), (float*)(ws + XRES),
      in_proj_b, 2048, 4096, 1024, 1024);

  // conv + silu
  conv_silu_kernel<<<(L_SEQ * DINNER) / 256, 256, 0, stream>>>(
      (const float*)(ws + XRES), conv_w, conv_b, (float*)(ws + U), (unsigned short*)(ws + UB));

  // G3: dbc += u @ x_proj_w  (M=2048,N=128,K=2048, split-K=16 w/ atomics)
  gemm_bf16_128<2><<<dim3(16, 1, 16), 256, 0, stream>>>(
      (const unsigned short*)(ws + UB), (const unsigned short*)(ws + W3T), (float*)(ws + DBC),
      nullptr, 2048, NPROJ_PAD, 2048, 128);

  cast_dt_kernel<<<(L_SEQ * DTRANK) / 256, 256, 0, stream>>>((const float*)(ws + DBC),
                                                             (unsigned short*)(ws + DTB));

  // G5: delta = softplus(dt @ dt_proj_w + b)  (M=2048,N=2048,K=64)
  gemm_bf16_128<1><<<dim3(16, 16, 1), 256, 0, stream>>>(
      (const unsigned short*)(ws + DTB), (const unsigned short*)(ws + W4T), (float*)(ws + DELTA),
      dt_proj_b, 2048, 2048, 64, 64);

  // selective scan
  const dim3 sgrid(DINNER / 256, nch);
  if (tch == 16) {
    scan1_kernel<16><<<sgrid, 256, 0, stream>>>(
        (const float*)(ws + DELTA), (const float*)(ws + U), (const float*)(ws + DBC), A_log,
        (float*)(ws + PBUF), (float*)(ws + HZB));
  } else if (tch == 32) {
    scan1_kernel<32><<<sgrid, 256, 0, stream>>>(
        (const float*)(ws + DELTA), (const float*)(ws + U), (const float*)(ws + DBC), A_log,
        (float*)(ws + PBUF), (float*)(ws + HZB));
  } else {
    scan1_kernel<64><<<sgrid, 256, 0, stream>>>(
        (const float*)(ws + DELTA), (const float*)(ws + U), (const float*)(ws + DBC), A_log,
        (float*)(ws + PBUF), (float*)(ws + HZB));
  }
  scan_carry_kernel<<<(NSTATE * DINNER) / 256, 256, 0, stream>>>(
      (const float*)(ws + PBUF), (const float*)(ws + HZB), (float*)(ws + H0B), nch);
  if (tch == 16) {
    scan2_kernel<16><<<sgrid, 256, 0, stream>>>(
        (const float*)(ws + DELTA), (const float*)(ws + U), (const float*)(ws + DBC), A_log, Dvec,
        (const float*)(ws + XRES), (const float*)(ws + H0B), (unsigned short*)(ws + YGB));
  } else if (tch == 32) {
    scan2_kernel<32><<<sgrid, 256, 0, stream>>>(
        (const float*)(ws + DELTA), (const float*)(ws + U), (const float*)(ws + DBC), A_log, Dvec,
        (const float*)(ws + XRES), (const float*)(ws + H0B), (unsigned short*)(ws + YGB));
  } else {
    scan2_kernel<64><<<sgrid, 256, 0, stream>>>(
        (const float*)(ws + DELTA), (const float*)(ws + U), (const float*)(ws + DBC), A_log, Dvec,
        (const float*)(ws + XRES), (const float*)(ws + H0B), (unsigned short*)(ws + YGB));
  }

  // G2: out = yg @ out_proj_w + b  (M=2048,N=1024,K=2048)
  gemm_bf16_128<0><<<dim3(16, 8, 1), 256, 0, stream>>>(
      (const unsigned short*)(ws + YGB), (const unsigned short*)(ws + W5T), out, out_proj_b, 2048,
      1024, 2048, 2048);
}

// Round 4
// 287.320 us; speedup vs baseline: 1.0993x; 1.0060x over previous
//
#include <hip/hip_runtime.h>

// Mamba block fused pipeline, MI355X gfx950.
// B=1, L=2048, D_MODEL=1024, D_INNER=2048, D_CONV=4, DT_RANK=64, D_STATE=16.
//
// R3 changes (GEMM template): double-buffered LDS with post-barrier prefetch
// (one barrier/iter, tile k+1 loads fly during tile k MFMA), XOR-swizzled 16B
// k-chunks to cut ds_read_b128 bank conflicts, split-K=4 atomic path for G2
// (out pre-initialized with bias). R2's G2 was 44us at 3% VALUBusy: 128 blocks,
// zero load/compute overlap.

#define L_SEQ 2048
#define DMODEL 1024
#define DINNER 2048
#define NSTATE 16
#define DTRANK 64
#define NPROJ_PAD 128

typedef __attribute__((ext_vector_type(8))) short short8;
typedef __attribute__((ext_vector_type(4))) float f32x4;

__device__ __forceinline__ unsigned short f2bf(float f) {
  unsigned int u = __float_as_uint(f);
  u += 0x7FFFu + ((u >> 16) & 1u);  // round-to-nearest-even
  return (unsigned short)(u >> 16);
}

__device__ __forceinline__ void gload16(const void* g, void* l) {
  // async global->LDS, 16B per lane; LDS dest = wave-uniform base + lane*16
  __builtin_amdgcn_global_load_lds((const __attribute__((address_space(1))) void*)g,
                                   (__attribute__((address_space(3))) void*)l, 16, 0, 0);
}

// ---------------- elementwise / prep kernels ----------------

__global__ void cast_bf16_kernel(const float* __restrict__ in, unsigned short* __restrict__ out,
                                 int n) {
  int id = blockIdx.x * 256 + threadIdx.x;
  if (id < n) out[id] = f2bf(in[id]);
}

// out[row, col] = bias[col]  (N power of two)
__global__ void bias_init_kernel(float* __restrict__ out, const float* __restrict__ b, int nmask) {
  int id = blockIdx.x * 256 + threadIdx.x;
  out[id] = b[id & nmask];
}

// dt slice (cols 0..63 of dbc row stride 128) -> contiguous bf16 (2048x64)
__global__ void cast_dt_kernel(const float* __restrict__ dbc, unsigned short* __restrict__ dtb) {
  int id = blockIdx.x * 256 + threadIdx.x;  // 2048*64
  int t = id >> 6, k = id & 63;
  dtb[id] = f2bf(dbc[t * NPROJ_PAD + k]);
}

// in (R x C fp32) -> out (C x R bf16)
__global__ void transpose_cast_kernel(const float* __restrict__ in,
                                      unsigned short* __restrict__ out, int R, int C) {
  __shared__ float tile[32][33];
  const int c0 = blockIdx.x * 32, r0 = blockIdx.y * 32;
  const int tx = threadIdx.x, ty = threadIdx.y;  // block (32,8)
  for (int y = ty; y < 32; y += 8) tile[y][tx] = in[(size_t)(r0 + y) * C + c0 + tx];
  __syncthreads();
  for (int y = ty; y < 32; y += 8) out[(size_t)(c0 + y) * R + r0 + tx] = f2bf(tile[tx][y]);
}

// depthwise causal conv (4 taps) + silu; u fp32 for scan, bf16 for GEMM3
__global__ void conv_silu_kernel(const float* __restrict__ xres, const float* __restrict__ cw,
                                 const float* __restrict__ cb, float* __restrict__ u,
                                 unsigned short* __restrict__ ub) {
  const int id = blockIdx.x * 256 + threadIdx.x;  // over 2048*2048
  const int t = id >> 11;
  const int d = id & (DINNER - 1);
  float acc = cb[d];
#pragma unroll
  for (int j = 0; j < 4; j++) {
    int tt = t - 3 + j;
    if (tt >= 0) acc += xres[(size_t)tt * (2 * DINNER) + d] * cw[j * DINNER + d];
  }
  float s = acc / (1.f + __expf(-acc));  // silu
  u[id] = s;
  ub[id] = f2bf(s);
}

// ---------------- bf16 MFMA GEMM: C[M,N] = A[M,K] @ Bt[N,K]^T ----------------
// 128x128 tile, BK=32, 4 waves each 64x64 of 16x16x32 MFMA frags.
// Double-buffered LDS: tile k+1 staged right after the (single) barrier so its
// global_load_lds stay in flight across tile k's ds_read+MFMA. 16B k-chunks
// XOR-swizzled by row&3 (staging source and reader agree) for bank spread.
// EPI: 0 = store acc+bias (bias may be null), 1 = store softplus(acc+bias),
//      2 = atomicAdd(C, acc) for split-K (grid.z = K/KS splits).
template <int EPI>
__global__ void gemm_bf16_128(const unsigned short* __restrict__ A,
                              const unsigned short* __restrict__ Bt, float* __restrict__ C,
                              const float* __restrict__ bias, int M, int N, int K, int KS) {
  __shared__ __align__(16) unsigned short lA[2][128 * 32];
  __shared__ __align__(16) unsigned short lB[2][128 * 32];
  const int tid = threadIdx.x;
  const int w = tid >> 6;
  const int lane = tid & 63;
  const int m0 = blockIdx.x * 128;
  const int n0 = blockIdx.y * 128;
  const int kbase = blockIdx.z * KS;
  const int lr = lane >> 2;  // row within 16-row group the lane stages
  // swizzled source k-chunk: physical chunk (lane&3) holds logical (lane&3)^(lr&3)
  const int srcoff = (((lane & 3) ^ (lr & 3)) * 8);
  const int wm = (w & 1) * 64;
  const int wn = (w >> 1) * 64;
  const int ml = lane & 15;
  const int quad = lane >> 4;
  const int qoff = (quad ^ (ml & 3)) * 8;  // reader-side swizzle (row&3 == ml&3)

  f32x4 acc[4][4];
#pragma unroll
  for (int i = 0; i < 4; i++)
#pragma unroll
    for (int j = 0; j < 4; j++) acc[i][j] = (f32x4){0.f, 0.f, 0.f, 0.f};

  const unsigned short* Ag = A + (size_t)m0 * K + kbase;
  const unsigned short* Bg = Bt + (size_t)n0 * K + kbase;

  const int niter = KS >> 5;  // KS/32
  auto stage = [&](int buf, int kk) {
    gload16(Ag + (size_t)(w * 16 + lr) * K + kk + srcoff, &lA[buf][(w * 16) * 32]);
    gload16(Ag + (size_t)(64 + w * 16 + lr) * K + kk + srcoff, &lA[buf][(64 + w * 16) * 32]);
    gload16(Bg + (size_t)(w * 16 + lr) * K + kk + srcoff, &lB[buf][(w * 16) * 32]);
    gload16(Bg + (size_t)(64 + w * 16 + lr) * K + kk + srcoff, &lB[buf][(64 + w * 16) * 32]);
  };

  stage(0, 0);
  for (int it = 0; it < niter; it++) {
    __syncthreads();  // drains tile-it loads (per-wave vmcnt(0) + barrier)
    if (it + 1 < niter) stage((it + 1) & 1, (it + 1) << 5);  // prefetch overlaps MFMA below
    const unsigned short* bufA = lA[it & 1];
    const unsigned short* bufB = lB[it & 1];
    short8 af[4], bfr[4];
#pragma unroll
    for (int i = 0; i < 4; i++) af[i] = *(const short8*)&bufA[(wm + i * 16 + ml) * 32 + qoff];
#pragma unroll
    for (int j = 0; j < 4; j++) bfr[j] = *(const short8*)&bufB[(wn + j * 16 + ml) * 32 + qoff];
#pragma unroll
    for (int i = 0; i < 4; i++)
#pragma unroll
      for (int j = 0; j < 4; j++)
        acc[i][j] = __builtin_amdgcn_mfma_f32_16x16x32_bf16(af[i], bfr[j], acc[i][j], 0, 0, 0);
  }

  // epilogue: C/D layout col = lane&15, row = quad*4 + r
#pragma unroll
  for (int i = 0; i < 4; i++) {
#pragma unroll
    for (int j = 0; j < 4; j++) {
      const int col = n0 + wn + j * 16 + ml;
      float bv = 0.f;
      if (EPI != 2 && bias != nullptr) bv = bias[col];
#pragma unroll
      for (int r = 0; r < 4; r++) {
        const int row = m0 + wm + i * 16 + quad * 4 + r;
        float v = acc[i][j][r];
        if (EPI == 2) {
          atomicAdd(&C[(size_t)row * N + col], v);
        } else {
          v += bv;
          if (EPI == 1) v = (v > 15.f) ? v : __logf(1.f + __expf(v));
          C[(size_t)row * N + col] = v;
        }
      }
    }
  }
}

// ---------------- selective scan (chunked 2-pass) ----------------
// Thread = one channel d within one chunk; 16 states in registers.
// TCH_T compile-time so the t-loop fully unrolls: all chunk loads issue ahead
// of the exp/fma chain (one global latency per chunk, not per timestep).

template <int TCH_T>
__global__ void scan1_kernel(const float* __restrict__ delta, const float* __restrict__ u,
                             const float* __restrict__ dbc, const float* __restrict__ A_log,
                             float* __restrict__ P, float* __restrict__ Hz) {
  __shared__ float Bs[TCH_T][NSTATE];
  const int d = blockIdx.x * 256 + threadIdx.x;
  const int c = blockIdx.y;
  for (int idx = threadIdx.x; idx < TCH_T * NSTATE; idx += 256) {
    int t = idx >> 4, n = idx & 15;
    Bs[t][n] = dbc[(size_t)(c * TCH_T + t) * NPROJ_PAD + DTRANK + n];
  }
  float Ad[16], h[16], p[16];
#pragma unroll
  for (int n = 0; n < 16; n++) {
    Ad[n] = -__expf(A_log[d * 16 + n]);
    h[n] = 0.f;
    p[n] = 1.f;
  }
  __syncthreads();
#pragma unroll
  for (int t = 0; t < TCH_T; t++) {
    const int tt = c * TCH_T + t;
    float dl = delta[(size_t)tt * DINNER + d];
    float uu = u[(size_t)tt * DINNER + d];
    float du = dl * uu;
#pragma unroll
    for (int n = 0; n < 16; n++) {
      float dA = __expf(dl * Ad[n]);
      p[n] *= dA;
      h[n] = dA * h[n] + du * Bs[t][n];
    }
  }
#pragma unroll
  for (int n = 0; n < 16; n++) {
    P[(size_t)(c * 16 + n) * DINNER + d] = p[n];
    Hz[(size_t)(c * 16 + n) * DINNER + d] = h[n];
  }
}

__global__ void scan_carry_kernel(const float* __restrict__ P, const float* __restrict__ Hz,
                                  float* __restrict__ H0, int nchunk) {
  const int id = blockIdx.x * 256 + threadIdx.x;  // 16*2048 (n,d) pairs
  float h = 0.f;
#pragma unroll 8
  for (int c = 0; c < nchunk; c++) {
    H0[c * (NSTATE * DINNER) + id] = h;
    h = P[c * (NSTATE * DINNER) + id] * h + Hz[c * (NSTATE * DINNER) + id];
  }
}

template <int TCH_T>
__global__ void scan2_kernel(const float* __restrict__ delta, const float* __restrict__ u,
                             const float* __restrict__ dbc, const float* __restrict__ A_log,
                             const float* __restrict__ Dv, const float* __restrict__ xres,
                             const float* __restrict__ H0, unsigned short* __restrict__ ygb) {
  __shared__ float Bs[TCH_T][NSTATE];
  __shared__ float Cs[TCH_T][NSTATE];
  const int d = blockIdx.x * 256 + threadIdx.x;
  const int c = blockIdx.y;
  for (int idx = threadIdx.x; idx < TCH_T * 2 * NSTATE; idx += 256) {
    int t = idx >> 5, q = idx & 31;
    float v = dbc[(size_t)(c * TCH_T + t) * NPROJ_PAD + DTRANK + q];
    if (q < 16) Bs[t][q] = v;
    else Cs[t][q - 16] = v;
  }
  float Ad[16], h[16];
#pragma unroll
  for (int n = 0; n < 16; n++) {
    Ad[n] = -__expf(A_log[d * 16 + n]);
    h[n] = H0[(size_t)(c * 16 + n) * DINNER + d];
  }
  const float Dd = Dv[d];
  __syncthreads();
#pragma unroll
  for (int t = 0; t < TCH_T; t++) {
    const int tt = c * TCH_T + t;
    float dl = delta[(size_t)tt * DINNER + d];
    float uu = u[(size_t)tt * DINNER + d];
    float r = xres[(size_t)tt * (2 * DINNER) + DINNER + d];
    float du = dl * uu;
    float y0 = 0.f, y1 = 0.f;
#pragma unroll
    for (int n = 0; n < 16; n++) {
      float dA = __expf(dl * Ad[n]);
      h[n] = dA * h[n] + du * Bs[t][n];
      if (n & 1) y1 += h[n] * Cs[t][n];
      else y0 += h[n] * Cs[t][n];
    }
    float sil = r / (1.f + __expf(-r));
    float yg = (y0 + y1 + uu * Dd) * sil;
    ygb[(size_t)tt * DINNER + d] = f2bf(yg);
  }
}

// ---------------- launch ----------------

extern "C" void kernel_launch(void* const* d_in, const int* in_sizes, int n_in, void* d_out,
                              int out_size, void* d_ws, size_t ws_size, hipStream_t stream) {
  const float* x = (const float*)d_in[0];
  const float* in_proj_w = (const float*)d_in[1];
  const float* in_proj_b = (const float*)d_in[2];
  const float* conv_w = (const float*)d_in[3];
  const float* conv_b = (const float*)d_in[4];
  const float* x_proj_w = (const float*)d_in[5];
  const float* dt_proj_w = (const float*)d_in[6];
  const float* dt_proj_b = (const float*)d_in[7];
  const float* A_log = (const float*)d_in[8];
  const float* Dvec = (const float*)d_in[9];
  const float* out_proj_w = (const float*)d_in[10];
  const float* out_proj_b = (const float*)d_in[11];
  float* out = (float*)d_out;
  char* ws = (char*)d_ws;

  // workspace layout (bytes), all 256-aligned
  const size_t MB = 1048576;
  const size_t XB = 0;                 // 2048x1024 bf16   4 MiB
  const size_t W1T = 4 * MB;           // 4096x1024 bf16   8 MiB
  const size_t XRES = 12 * MB;         // 2048x4096 fp32  32 MiB
  const size_t U = 44 * MB;            // 2048x2048 fp32  16 MiB
  const size_t UB = 60 * MB;           // 2048x2048 bf16   8 MiB
  const size_t W3T = 68 * MB;          // 128x2048 bf16  0.5 MiB
  const size_t DBC = W3T + 524288;     // 2048x128 fp32    1 MiB
  const size_t DTB = DBC + MB;         // 2048x64 bf16  0.25 MiB
  const size_t W4T = DTB + 262144;     // 2048x64 bf16  0.25 MiB
  const size_t DELTA = 70 * MB;        // 2048x2048 fp32  16 MiB
  const size_t YGB = 86 * MB;          // 2048x2048 bf16   8 MiB
  const size_t W5T = 94 * MB;          // 1024x2048 bf16   4 MiB
  const size_t PBUF = 98 * MB;         // [nch x 16 x 2048] fp32
  (void)in_sizes; (void)n_in; (void)out_size;

  // tier chunk count on available workspace: need PBUF + 3*PB bytes
  int tch = 64;
  if (ws_size >= PBUF + 3 * (size_t)(128 * NSTATE * DINNER) * 4) tch = 16;       // 146 MiB
  else if (ws_size >= PBUF + 3 * (size_t)(64 * NSTATE * DINNER) * 4) tch = 32;   // 122 MiB
  const int nch = L_SEQ / tch;
  const size_t PB = (size_t)nch * NSTATE * DINNER * 4;
  const size_t HZB = PBUF + PB;
  const size_t H0B = PBUF + 2 * PB;

  // zero pad rows of w3t and the split-K accumulator
  hipMemsetAsync(ws + W3T, 0, NPROJ_PAD * DINNER * 2, stream);
  hipMemsetAsync(ws + DBC, 0, (size_t)L_SEQ * NPROJ_PAD * 4, stream);

  // prep casts
  cast_bf16_kernel<<<(L_SEQ * DMODEL) / 256, 256, 0, stream>>>(x, (unsigned short*)(ws + XB),
                                                               L_SEQ * DMODEL);
  transpose_cast_kernel<<<dim3(4096 / 32, 1024 / 32), dim3(32, 8), 0, stream>>>(
      in_proj_w, (unsigned short*)(ws + W1T), 1024, 4096);
  transpose_cast_kernel<<<dim3(96 / 32, 2048 / 32), dim3(32, 8), 0, stream>>>(
      x_proj_w, (unsigned short*)(ws + W3T), 2048, 96);
  transpose_cast_kernel<<<dim3(2048 / 32, 64 / 32), dim3(32, 8), 0, stream>>>(
      dt_proj_w, (unsigned short*)(ws + W4T), 64, 2048);
  transpose_cast_kernel<<<dim3(1024 / 32, 2048 / 32), dim3(32, 8), 0, stream>>>(
      out_proj_w, (unsigned short*)(ws + W5T), 2048, 1024);

  // G1: xres = x @ in_proj_w + b   (M=2048,N=4096,K=1024)
  gemm_bf16_128<0><<<dim3(16, 32, 1), 256, 0, stream>>>(
      (const unsigned short*)(ws + XB), (const unsigned short*)(ws + W1T), (float*)(ws + XRES),
      in_proj_b, 2048, 4096, 1024, 1024);

  // conv + silu
  conv_silu_kernel<<<(L_SEQ * DINNER) / 256, 256, 0, stream>>>(
      (const float*)(ws + XRES), conv_w, conv_b, (float*)(ws + U), (unsigned short*)(ws + UB));

  // G3: dbc += u @ x_proj_w  (M=2048,N=128,K=2048, split-K=16 w/ atomics)
  gemm_bf16_128<2><<<dim3(16, 1, 16), 256, 0, stream>>>(
      (const unsigned short*)(ws + UB), (const unsigned short*)(ws + W3T), (float*)(ws + DBC),
      nullptr, 2048, NPROJ_PAD, 2048, 128);

  cast_dt_kernel<<<(L_SEQ * DTRANK) / 256, 256, 0, stream>>>((const float*)(ws + DBC),
                                                             (unsigned short*)(ws + DTB));

  // G5: delta = softplus(dt @ dt_proj_w + b)  (M=2048,N=2048,K=64)
  gemm_bf16_128<1><<<dim3(16, 16, 1), 256, 0, stream>>>(
      (const unsigned short*)(ws + DTB), (const unsigned short*)(ws + W4T), (float*)(ws + DELTA),
      dt_proj_b, 2048, 2048, 64, 64);

  // selective scan
  const dim3 sgrid(DINNER / 256, nch);
  if (tch == 16) {
    scan1_kernel<16><<<sgrid, 256, 0, stream>>>(
        (const float*)(ws + DELTA), (const float*)(ws + U), (const float*)(ws + DBC), A_log,
        (float*)(ws + PBUF), (float*)(ws + HZB));
  } else if (tch == 32) {
    scan1_kernel<32><<<sgrid, 256, 0, stream>>>(
        (const float*)(ws + DELTA), (const float*)(ws + U), (const float*)(ws + DBC), A_log,
        (float*)(ws + PBUF), (float*)(ws + HZB));
  } else {
    scan1_kernel<64><<<sgrid, 256, 0, stream>>>(
        (const float*)(ws + DELTA), (const float*)(ws + U), (const float*)(ws + DBC), A_log,
        (float*)(ws + PBUF), (float*)(ws + HZB));
  }
  scan_carry_kernel<<<(NSTATE * DINNER) / 256, 256, 0, stream>>>(
      (const float*)(ws + PBUF), (const float*)(ws + HZB), (float*)(ws + H0B), nch);
  if (tch == 16) {
    scan2_kernel<16><<<sgrid, 256, 0, stream>>>(
        (const float*)(ws + DELTA), (const float*)(ws + U), (const float*)(ws + DBC), A_log, Dvec,
        (const float*)(ws + XRES), (const float*)(ws + H0B), (unsigned short*)(ws + YGB));
  } else if (tch == 32) {
    scan2_kernel<32><<<sgrid, 256, 0, stream>>>(
        (const float*)(ws + DELTA), (const float*)(ws + U), (const float*)(ws + DBC), A_log, Dvec,
        (const float*)(ws + XRES), (const float*)(ws + H0B), (unsigned short*)(ws + YGB));
  } else {
    scan2_kernel<64><<<sgrid, 256, 0, stream>>>(
        (const float*)(ws + DELTA), (const float*)(ws + U), (const float*)(ws + DBC), A_log, Dvec,
        (const float*)(ws + XRES), (const float*)(ws + H0B), (unsigned short*)(ws + YGB));
  }

  // G2: out = yg @ out_proj_w + b  (M=2048,N=1024,K=2048, split-K=4 w/ atomics,
  // out pre-initialized with bias)
  bias_init_kernel<<<(L_SEQ * DMODEL) / 256, 256, 0, stream>>>(out, out_proj_b, DMODEL - 1);
  gemm_bf16_128<2><<<dim3(16, 8, 4), 256, 0, stream>>>(
      (const unsigned short*)(ws + YGB), (const unsigned short*)(ws + W5T), out, nullptr, 2048,
      1024, 2048, 512);
}

// Round 5
// 238.810 us; speedup vs baseline: 1.3226x; 1.2031x over previous
//
#include <hip/hip_runtime.h>

// Mamba block fused pipeline, MI355X gfx950.
// B=1, L=2048, D_MODEL=1024, D_INNER=2048, D_CONV=4, DT_RANK=64, D_STATE=16.
//
// R5: no global atomics (split-K via partial buffers + reduce kernels),
// GEMM BK=64 double-buffer (half the barrier drains of BK=32) with XOR bank
// swizzle, all prep (cast + 4 transposes + pad-zero) in ONE kernel,
// cast_dt folded into reduce_dbc, bias folded into reduce_out.
// 11 dispatches total (was 16).

#define L_SEQ 2048
#define DMODEL 1024
#define DINNER 2048
#define NSTATE 16
#define DTRANK 64
#define NPROJ_PAD 128

typedef __attribute__((ext_vector_type(8))) short short8;
typedef __attribute__((ext_vector_type(4))) float f32x4;

__device__ __forceinline__ unsigned short f2bf(float f) {
  unsigned int u = __float_as_uint(f);
  u += 0x7FFFu + ((u >> 16) & 1u);  // round-to-nearest-even
  return (unsigned short)(u >> 16);
}

__device__ __forceinline__ void gload16(const void* g, void* l) {
  // async global->LDS, 16B per lane; LDS dest = wave-uniform base + lane*16
  __builtin_amdgcn_global_load_lds((const __attribute__((address_space(1))) void*)g,
                                   (__attribute__((address_space(3))) void*)l, 16, 0, 0);
}

// ---------------- unified prep kernel ----------------
// block = (32,8). Jobs by blockIdx.x:
//  [0,4096)    transpose in_proj_w  (1024x4096 -> 4096x1024 bf16)
//  [4096,4288) transpose x_proj_w   (2048x96   -> 96x2048  bf16)
//  [4288,4416) transpose dt_proj_w  (64x2048   -> 2048x64  bf16)
//  [4416,6464) transpose out_proj_w (2048x1024 -> 1024x2048 bf16)
//  [6464,8512) cast x fp32 -> bf16 (float4 -> ushort4)
//  [8512,8544) zero w3t pad rows 96..127
__global__ void prep_kernel(const float* __restrict__ in_proj_w, const float* __restrict__ x_proj_w,
                            const float* __restrict__ dt_proj_w,
                            const float* __restrict__ out_proj_w, const float* __restrict__ x,
                            unsigned short* __restrict__ w1t, unsigned short* __restrict__ w3t,
                            unsigned short* __restrict__ w4t, unsigned short* __restrict__ w5t,
                            unsigned short* __restrict__ xb) {
  const int bx = blockIdx.x;
  const int tx = threadIdx.x, ty = threadIdx.y;
  const int id = ty * 32 + tx;

  if (bx >= 6464) {
    if (bx < 8512) {  // cast x
      const int fid = (bx - 6464) * 256 + id;
      f32x4 v = ((const f32x4*)x)[fid];
      ushort4 o;
      o.x = f2bf(v.x); o.y = f2bf(v.y); o.z = f2bf(v.z); o.w = f2bf(v.w);
      ((ushort4*)xb)[fid] = o;
    } else {  // zero w3t pad rows [96,128)
      const int fid = (bx - 8512) * 256 + id;
      ((uint4*)(w3t + 96 * 2048))[fid] = (uint4){0, 0, 0, 0};
    }
    return;
  }

  // transpose jobs
  const float* in;
  unsigned short* out;
  int R, C, rel, gx;
  if (bx < 4096) { in = in_proj_w; out = w1t; R = 1024; C = 4096; rel = bx; gx = 128; }
  else if (bx < 4288) { in = x_proj_w; out = w3t; R = 2048; C = 96; rel = bx - 4096; gx = 3; }
  else if (bx < 4416) { in = dt_proj_w; out = w4t; R = 64; C = 2048; rel = bx - 4288; gx = 64; }
  else { in = out_proj_w; out = w5t; R = 2048; C = 1024; rel = bx - 4416; gx = 32; }
  const int c0 = (rel % gx) * 32, r0 = (rel / gx) * 32;

  __shared__ float tile[32][33];
  for (int y = ty; y < 32; y += 8) tile[y][tx] = in[(size_t)(r0 + y) * C + c0 + tx];
  __syncthreads();
  for (int y = ty; y < 32; y += 8) out[(size_t)(c0 + y) * R + r0 + tx] = f2bf(tile[tx][y]);
}

// depthwise causal conv (4 taps) + silu; u fp32 for scan, bf16 for GEMM3
__global__ void conv_silu_kernel(const float* __restrict__ xres, const float* __restrict__ cw,
                                 const float* __restrict__ cb, float* __restrict__ u,
                                 unsigned short* __restrict__ ub) {
  const int id = blockIdx.x * 256 + threadIdx.x;  // over 2048*2048
  const int t = id >> 11;
  const int d = id & (DINNER - 1);
  float acc = cb[d];
#pragma unroll
  for (int j = 0; j < 4; j++) {
    int tt = t - 3 + j;
    if (tt >= 0) acc += xres[(size_t)tt * (2 * DINNER) + d] * cw[j * DINNER + d];
  }
  float s = acc / (1.f + __expf(-acc));  // silu
  u[id] = s;
  ub[id] = f2bf(s);
}

// ---------------- bf16 MFMA GEMM: C[M,N] = A[M,K] @ Bt[N,K]^T ----------------
// 128x128 tile, BK=64 (2 k-steps per barrier), double-buffered LDS with
// post-barrier prefetch. Rows are 128B in LDS; 16B chunks XOR-swizzled by
// row&7 so frag reads spread across bank windows (2-way max = free).
// EPI: 0 = store acc+bias (bias may be null), 1 = store softplus(acc+bias),
//      2 = atomicAdd (fallback split-K), 3 = plain store to partial buffer
//          C + blockIdx.z*M*N (split-K, reduced later).
template <int EPI>
__global__ void gemm_bf16(const unsigned short* __restrict__ A,
                          const unsigned short* __restrict__ Bt, float* __restrict__ C,
                          const float* __restrict__ bias, int M, int N, int K, int KS) {
  __shared__ __align__(16) unsigned short lA[2][128 * 64];
  __shared__ __align__(16) unsigned short lB[2][128 * 64];
  const int tid = threadIdx.x;
  const int w = tid >> 6;
  const int lane = tid & 63;
  const int m0 = blockIdx.x * 128;
  const int n0 = blockIdx.y * 128;
  const int kbase = blockIdx.z * KS;
  const int lr = lane >> 3;                       // row within 8-row staging group
  const int srcoff = ((lane & 7) ^ lr) * 8;       // swizzled source chunk (elems)
  const int wm = (w & 1) * 64;
  const int wn = (w >> 1) * 64;
  const int ml = lane & 15;
  const int quad = lane >> 4;

  f32x4 acc[4][4];
#pragma unroll
  for (int i = 0; i < 4; i++)
#pragma unroll
    for (int j = 0; j < 4; j++) acc[i][j] = (f32x4){0.f, 0.f, 0.f, 0.f};

  const unsigned short* Ag = A + (size_t)m0 * K + kbase;
  const unsigned short* Bg = Bt + (size_t)n0 * K + kbase;

  const int niter = KS >> 6;  // KS/64
  auto stage = [&](int buf, int kk) {
#pragma unroll
    for (int c2 = 0; c2 < 4; c2++) {
      const int row = w * 32 + c2 * 8 + lr;
      gload16(Ag + (size_t)row * K + kk + srcoff, &lA[buf][(w * 32 + c2 * 8) * 64]);
      gload16(Bg + (size_t)row * K + kk + srcoff, &lB[buf][(w * 32 + c2 * 8) * 64]);
    }
  };

  stage(0, 0);
  for (int it = 0; it < niter; it++) {
    __syncthreads();
    if (it + 1 < niter) stage((it + 1) & 1, (it + 1) << 6);  // overlaps MFMA below
    const unsigned short* bufA = lA[it & 1];
    const unsigned short* bufB = lB[it & 1];
#pragma unroll
    for (int ks = 0; ks < 2; ks++) {
      short8 af[4], bfr[4];
#pragma unroll
      for (int i = 0; i < 4; i++) {
        const int row = wm + i * 16 + ml;
        const int q = ((ks * 4 + quad) ^ (ml & 7)) * 8;
        af[i] = *(const short8*)&bufA[row * 64 + q];
      }
#pragma unroll
      for (int j = 0; j < 4; j++) {
        const int row = wn + j * 16 + ml;
        const int q = ((ks * 4 + quad) ^ (ml & 7)) * 8;
        bfr[j] = *(const short8*)&bufB[row * 64 + q];
      }
#pragma unroll
      for (int i = 0; i < 4; i++)
#pragma unroll
        for (int j = 0; j < 4; j++)
          acc[i][j] = __builtin_amdgcn_mfma_f32_16x16x32_bf16(af[i], bfr[j], acc[i][j], 0, 0, 0);
    }
  }

  float* Cp = (EPI == 3) ? C + (size_t)blockIdx.z * M * N : C;
  // epilogue: C/D layout col = lane&15, row = quad*4 + r
#pragma unroll
  for (int i = 0; i < 4; i++) {
#pragma unroll
    for (int j = 0; j < 4; j++) {
      const int col = n0 + wn + j * 16 + ml;
      float bv = 0.f;
      if ((EPI == 0 || EPI == 1) && bias != nullptr) bv = bias[col];
#pragma unroll
      for (int r = 0; r < 4; r++) {
        const int row = m0 + wm + i * 16 + quad * 4 + r;
        float v = acc[i][j][r];
        if (EPI == 2) {
          atomicAdd(&Cp[(size_t)row * N + col], v);
        } else {
          v += bv;
          if (EPI == 1) v = (v > 15.f) ? v : __logf(1.f + __expf(v));
          Cp[(size_t)row * N + col] = v;
        }
      }
    }
  }
}

// sum 16 G3 partials -> dbc fp32; also emit dt slice (cols<64) as bf16
__global__ void reduce_dbc_kernel(const float* __restrict__ part, float* __restrict__ dbc,
                                  unsigned short* __restrict__ dtb) {
  const int id = blockIdx.x * 256 + threadIdx.x;  // 2048*128
  float s = 0.f;
#pragma unroll
  for (int z = 0; z < 16; z++) s += part[(size_t)z * (L_SEQ * NPROJ_PAD) + id];
  dbc[id] = s;
  const int col = id & 127;
  if (col < 64) dtb[(id >> 7) * 64 + col] = f2bf(s);
}

// sum 4 G2 partials + bias -> out (float4)
__global__ void reduce_out_kernel(const float* __restrict__ part, const float* __restrict__ bias,
                                  float* __restrict__ out) {
  const int fid = blockIdx.x * 256 + threadIdx.x;  // 512K float4
  const f32x4* p = (const f32x4*)part;
  const int stride = (L_SEQ * DMODEL) / 4;
  f32x4 v = p[fid];
  v += p[fid + stride];
  v += p[fid + 2 * stride];
  v += p[fid + 3 * stride];
  v += ((const f32x4*)bias)[fid & 255];
  ((f32x4*)out)[fid] = v;
}

// fallback helpers (small-ws path only)
__global__ void bias_init_kernel(float* __restrict__ out, const float* __restrict__ b, int nmask) {
  int id = blockIdx.x * 256 + threadIdx.x;
  out[id] = b[id & nmask];
}
__global__ void cast_dt_kernel(const float* __restrict__ dbc, unsigned short* __restrict__ dtb) {
  int id = blockIdx.x * 256 + threadIdx.x;
  int t = id >> 6, k = id & 63;
  dtb[id] = f2bf(dbc[t * NPROJ_PAD + k]);
}

// ---------------- selective scan (chunked 2-pass) ----------------

template <int TCH_T>
__global__ void scan1_kernel(const float* __restrict__ delta, const float* __restrict__ u,
                             const float* __restrict__ dbc, const float* __restrict__ A_log,
                             float* __restrict__ P, float* __restrict__ Hz) {
  __shared__ float Bs[TCH_T][NSTATE];
  const int d = blockIdx.x * 256 + threadIdx.x;
  const int c = blockIdx.y;
  for (int idx = threadIdx.x; idx < TCH_T * NSTATE; idx += 256) {
    int t = idx >> 4, n = idx & 15;
    Bs[t][n] = dbc[(size_t)(c * TCH_T + t) * NPROJ_PAD + DTRANK + n];
  }
  float Ad[16], h[16], p[16];
#pragma unroll
  for (int n = 0; n < 16; n++) {
    Ad[n] = -__expf(A_log[d * 16 + n]);
    h[n] = 0.f;
    p[n] = 1.f;
  }
  __syncthreads();
#pragma unroll
  for (int t = 0; t < TCH_T; t++) {
    const int tt = c * TCH_T + t;
    float dl = delta[(size_t)tt * DINNER + d];
    float uu = u[(size_t)tt * DINNER + d];
    float du = dl * uu;
#pragma unroll
    for (int n = 0; n < 16; n++) {
      float dA = __expf(dl * Ad[n]);
      p[n] *= dA;
      h[n] = dA * h[n] + du * Bs[t][n];
    }
  }
#pragma unroll
  for (int n = 0; n < 16; n++) {
    P[(size_t)(c * 16 + n) * DINNER + d] = p[n];
    Hz[(size_t)(c * 16 + n) * DINNER + d] = h[n];
  }
}

__global__ void scan_carry_kernel(const float* __restrict__ P, const float* __restrict__ Hz,
                                  float* __restrict__ H0, int nchunk) {
  const int id = blockIdx.x * 256 + threadIdx.x;  // 16*2048 (n,d) pairs
  float h = 0.f;
#pragma unroll 8
  for (int c = 0; c < nchunk; c++) {
    H0[c * (NSTATE * DINNER) + id] = h;
    h = P[c * (NSTATE * DINNER) + id] * h + Hz[c * (NSTATE * DINNER) + id];
  }
}

template <int TCH_T>
__global__ void scan2_kernel(const float* __restrict__ delta, const float* __restrict__ u,
                             const float* __restrict__ dbc, const float* __restrict__ A_log,
                             const float* __restrict__ Dv, const float* __restrict__ xres,
                             const float* __restrict__ H0, unsigned short* __restrict__ ygb) {
  __shared__ float Bs[TCH_T][NSTATE];
  __shared__ float Cs[TCH_T][NSTATE];
  const int d = blockIdx.x * 256 + threadIdx.x;
  const int c = blockIdx.y;
  for (int idx = threadIdx.x; idx < TCH_T * 2 * NSTATE; idx += 256) {
    int t = idx >> 5, q = idx & 31;
    float v = dbc[(size_t)(c * TCH_T + t) * NPROJ_PAD + DTRANK + q];
    if (q < 16) Bs[t][q] = v;
    else Cs[t][q - 16] = v;
  }
  float Ad[16], h[16];
#pragma unroll
  for (int n = 0; n < 16; n++) {
    Ad[n] = -__expf(A_log[d * 16 + n]);
    h[n] = H0[(size_t)(c * 16 + n) * DINNER + d];
  }
  const float Dd = Dv[d];
  __syncthreads();
#pragma unroll
  for (int t = 0; t < TCH_T; t++) {
    const int tt = c * TCH_T + t;
    float dl = delta[(size_t)tt * DINNER + d];
    float uu = u[(size_t)tt * DINNER + d];
    float r = xres[(size_t)tt * (2 * DINNER) + DINNER + d];
    float du = dl * uu;
    float y0 = 0.f, y1 = 0.f;
#pragma unroll
    for (int n = 0; n < 16; n++) {
      float dA = __expf(dl * Ad[n]);
      h[n] = dA * h[n] + du * Bs[t][n];
      if (n & 1) y1 += h[n] * Cs[t][n];
      else y0 += h[n] * Cs[t][n];
    }
    float sil = r / (1.f + __expf(-r));
    float yg = (y0 + y1 + uu * Dd) * sil;
    ygb[(size_t)tt * DINNER + d] = f2bf(yg);
  }
}

// ---------------- launch ----------------

extern "C" void kernel_launch(void* const* d_in, const int* in_sizes, int n_in, void* d_out,
                              int out_size, void* d_ws, size_t ws_size, hipStream_t stream) {
  const float* x = (const float*)d_in[0];
  const float* in_proj_w = (const float*)d_in[1];
  const float* in_proj_b = (const float*)d_in[2];
  const float* conv_w = (const float*)d_in[3];
  const float* conv_b = (const float*)d_in[4];
  const float* x_proj_w = (const float*)d_in[5];
  const float* dt_proj_w = (const float*)d_in[6];
  const float* dt_proj_b = (const float*)d_in[7];
  const float* A_log = (const float*)d_in[8];
  const float* Dvec = (const float*)d_in[9];
  const float* out_proj_w = (const float*)d_in[10];
  const float* out_proj_b = (const float*)d_in[11];
  float* out = (float*)d_out;
  char* ws = (char*)d_ws;

  // workspace layout (bytes)
  const size_t MB = 1048576;
  const size_t XB = 0;                 // 2048x1024 bf16   4 MiB
  const size_t W1T = 4 * MB;           // 4096x1024 bf16   8 MiB
  const size_t XRES = 12 * MB;         // 2048x4096 fp32  32 MiB
  const size_t U = 44 * MB;            // 2048x2048 fp32  16 MiB
  const size_t UB = 60 * MB;           // 2048x2048 bf16   8 MiB
  const size_t W3T = 68 * MB;          // 128x2048 bf16  0.5 MiB
  const size_t DBC = W3T + 524288;     // 2048x128 fp32    1 MiB
  const size_t DTB = DBC + MB;         // 2048x64 bf16  0.25 MiB
  const size_t W4T = DTB + 262144;     // 2048x64 bf16  0.25 MiB
  const size_t DELTA = 70 * MB;        // 2048x2048 fp32  16 MiB
  const size_t YGB = 86 * MB;          // 2048x2048 bf16   8 MiB
  const size_t W5T = 94 * MB;          // 1024x2048 bf16   4 MiB
  const size_t PBUF = 98 * MB;         // scan P/Hz/H0; also reused for GEMM partials
  (void)in_sizes; (void)n_in; (void)out_size;

  const bool big = ws_size >= PBUF + 3 * (size_t)(128 * NSTATE * DINNER) * 4;  // 146 MiB
  // one prep kernel: 4 transposes + cast x + zero w3t pad
  prep_kernel<<<8544, dim3(32, 8), 0, stream>>>(
      in_proj_w, x_proj_w, dt_proj_w, out_proj_w, x, (unsigned short*)(ws + W1T),
      (unsigned short*)(ws + W3T), (unsigned short*)(ws + W4T), (unsigned short*)(ws + W5T),
      (unsigned short*)(ws + XB));

  // G1: xres = x @ in_proj_w + b   (M=2048,N=4096,K=1024)
  gemm_bf16<0><<<dim3(16, 32, 1), 256, 0, stream>>>(
      (const unsigned short*)(ws + XB), (const unsigned short*)(ws + W1T), (float*)(ws + XRES),
      in_proj_b, 2048, 4096, 1024, 1024);

  // conv + silu
  conv_silu_kernel<<<(L_SEQ * DINNER) / 256, 256, 0, stream>>>(
      (const float*)(ws + XRES), conv_w, conv_b, (float*)(ws + U), (unsigned short*)(ws + UB));

  if (big) {
    const int tch = 16, nch = 128;
    const size_t PB = (size_t)nch * NSTATE * DINNER * 4;  // 16 MiB
    const size_t HZB = PBUF + PB;
    const size_t H0B = PBUF + 2 * PB;
    const size_t G3P = PBUF;  // 16 partials x 1 MiB (dead before scan1 writes PBUF)
    const size_t G2P = PBUF;  // 4 partials x 8 MiB (used after scans are done)

    // G3: dbc partials (M=2048,N=128,K=2048, split-K=16, plain stores)
    gemm_bf16<3><<<dim3(16, 1, 16), 256, 0, stream>>>(
        (const unsigned short*)(ws + UB), (const unsigned short*)(ws + W3T), (float*)(ws + G3P),
        nullptr, 2048, NPROJ_PAD, 2048, 128);
    reduce_dbc_kernel<<<(L_SEQ * NPROJ_PAD) / 256, 256, 0, stream>>>(
        (const float*)(ws + G3P), (float*)(ws + DBC), (unsigned short*)(ws + DTB));

    // G5: delta = softplus(dt @ dt_proj_w + b)  (M=2048,N=2048,K=64)
    gemm_bf16<1><<<dim3(16, 16, 1), 256, 0, stream>>>(
        (const unsigned short*)(ws + DTB), (const unsigned short*)(ws + W4T), (float*)(ws + DELTA),
        dt_proj_b, 2048, 2048, 64, 64);

    // selective scan
    const dim3 sgrid(DINNER / 256, nch);
    scan1_kernel<16><<<sgrid, 256, 0, stream>>>(
        (const float*)(ws + DELTA), (const float*)(ws + U), (const float*)(ws + DBC), A_log,
        (float*)(ws + PBUF), (float*)(ws + HZB));
    scan_carry_kernel<<<(NSTATE * DINNER) / 256, 256, 0, stream>>>(
        (const float*)(ws + PBUF), (const float*)(ws + HZB), (float*)(ws + H0B), nch);
    scan2_kernel<16><<<sgrid, 256, 0, stream>>>(
        (const float*)(ws + DELTA), (const float*)(ws + U), (const float*)(ws + DBC), A_log, Dvec,
        (const float*)(ws + XRES), (const float*)(ws + H0B), (unsigned short*)(ws + YGB));

    // G2: out partials (M=2048,N=1024,K=2048, split-K=4), then reduce + bias
    gemm_bf16<3><<<dim3(16, 8, 4), 256, 0, stream>>>(
        (const unsigned short*)(ws + YGB), (const unsigned short*)(ws + W5T), (float*)(ws + G2P),
        nullptr, 2048, 1024, 2048, 512);
    reduce_out_kernel<<<(L_SEQ * DMODEL) / 1024, 256, 0, stream>>>((const float*)(ws + G2P),
                                                                   out_proj_b, out);
    (void)tch;
  } else {
    // fallback (small workspace): atomic split-K paths
    hipMemsetAsync(ws + DBC, 0, (size_t)L_SEQ * NPROJ_PAD * 4, stream);
    gemm_bf16<2><<<dim3(16, 1, 16), 256, 0, stream>>>(
        (const unsigned short*)(ws + UB), (const unsigned short*)(ws + W3T), (float*)(ws + DBC),
        nullptr, 2048, NPROJ_PAD, 2048, 128);
    cast_dt_kernel<<<(L_SEQ * DTRANK) / 256, 256, 0, stream>>>((const float*)(ws + DBC),
                                                               (unsigned short*)(ws + DTB));
    gemm_bf16<1><<<dim3(16, 16, 1), 256, 0, stream>>>(
        (const unsigned short*)(ws + DTB), (const unsigned short*)(ws + W4T), (float*)(ws + DELTA),
        dt_proj_b, 2048, 2048, 64, 64);
    const int tch = 64, nch = 32;
    const size_t PB = (size_t)nch * NSTATE * DINNER * 4;
    const size_t HZB = PBUF + PB;
    const size_t H0B = PBUF + 2 * PB;
    const dim3 sgrid(DINNER / 256, nch);
    scan1_kernel<64><<<sgrid, 256, 0, stream>>>(
        (const float*)(ws + DELTA), (const float*)(ws + U), (const float*)(ws + DBC), A_log,
        (float*)(ws + PBUF), (float*)(ws + HZB));
    scan_carry_kernel<<<(NSTATE * DINNER) / 256, 256, 0, stream>>>(
        (const float*)(ws + PBUF), (const float*)(ws + HZB), (float*)(ws + H0B), nch);
    scan2_kernel<64><<<sgrid, 256, 0, stream>>>(
        (const float*)(ws + DELTA), (const float*)(ws + U), (const float*)(ws + DBC), A_log, Dvec,
        (const float*)(ws + XRES), (const float*)(ws + H0B), (unsigned short*)(ws + YGB));
    bias_init_kernel<<<(L_SEQ * DMODEL) / 256, 256, 0, stream>>>(out, out_proj_b, DMODEL - 1);
    gemm_bf16<2><<<dim3(16, 8, 4), 256, 0, stream>>>(
        (const unsigned short*)(ws + YGB), (const unsigned short*)(ws + W5T), out, nullptr, 2048,
        1024, 2048, 512);
    (void)tch;
  }
}

// Round 6
// 230.501 us; speedup vs baseline: 1.3703x; 1.0360x over previous
//
#include <hip/hip_runtime.h>

// Mamba block fused pipeline, MI355X gfx950.
// B=1, L=2048, D_MODEL=1024, D_INNER=2048, D_CONV=4, DT_RANK=64, D_STATE=16.
//
// R6: traffic surgery. G1 dual epilogue (xin fp32 + silu(res) bf16 -> no XRES,
// scan2 reads pre-silu'd res in bf16), u kept bf16-only, delta bf16 (softplus
// epilogue casts), P/Hz/H0 carry buffers bf16 (chunk carry is ~e^-8 damped, no
// error accumulation), G2 direct 64x64-tile GEMM (512 blocks, bias fused, no
// split-K/reduce), G3 split-K 16->8 with 64-row tiles. ~460 -> ~250 MB moved.

#define L_SEQ 2048
#define DMODEL 1024
#define DINNER 2048
#define NSTATE 16
#define DTRANK 64
#define NPROJ_PAD 128
#define NCH 128
#define TCH 16

typedef __attribute__((ext_vector_type(8))) short short8;
typedef __attribute__((ext_vector_type(4))) float f32x4;

__device__ __forceinline__ unsigned short f2bf(float f) {
  unsigned int u = __float_as_uint(f);
  u += 0x7FFFu + ((u >> 16) & 1u);  // round-to-nearest-even
  return (unsigned short)(u >> 16);
}
__device__ __forceinline__ float bf2f(unsigned short u) {
  return __uint_as_float(((unsigned int)u) << 16);
}

__device__ __forceinline__ void gload16(const void* g, void* l) {
  // async global->LDS, 16B per lane; LDS dest = wave-uniform base + lane*16
  __builtin_amdgcn_global_load_lds((const __attribute__((address_space(1))) void*)g,
                                   (__attribute__((address_space(3))) void*)l, 16, 0, 0);
}

// ---------------- unified prep kernel ----------------
// block = (32,8). Jobs by blockIdx.x:
//  [0,4096)    transpose in_proj_w  (1024x4096 -> 4096x1024 bf16)
//  [4096,4288) transpose x_proj_w   (2048x96   -> 96x2048  bf16)
//  [4288,4416) transpose dt_proj_w  (64x2048   -> 2048x64  bf16)
//  [4416,6464) transpose out_proj_w (2048x1024 -> 1024x2048 bf16)
//  [6464,8512) cast x fp32 -> bf16
//  [8512,8544) zero w3t pad rows 96..127
__global__ void prep_kernel(const float* __restrict__ in_proj_w, const float* __restrict__ x_proj_w,
                            const float* __restrict__ dt_proj_w,
                            const float* __restrict__ out_proj_w, const float* __restrict__ x,
                            unsigned short* __restrict__ w1t, unsigned short* __restrict__ w3t,
                            unsigned short* __restrict__ w4t, unsigned short* __restrict__ w5t,
                            unsigned short* __restrict__ xb) {
  const int bx = blockIdx.x;
  const int tx = threadIdx.x, ty = threadIdx.y;
  const int id = ty * 32 + tx;

  if (bx >= 6464) {
    if (bx < 8512) {  // cast x
      const int fid = (bx - 6464) * 256 + id;
      f32x4 v = ((const f32x4*)x)[fid];
      ushort4 o;
      o.x = f2bf(v.x); o.y = f2bf(v.y); o.z = f2bf(v.z); o.w = f2bf(v.w);
      ((ushort4*)xb)[fid] = o;
    } else {  // zero w3t pad rows [96,128)
      const int fid = (bx - 8512) * 256 + id;
      ((uint4*)(w3t + 96 * 2048))[fid] = (uint4){0, 0, 0, 0};
    }
    return;
  }

  const float* in;
  unsigned short* out;
  int R, C, rel, gx;
  if (bx < 4096) { in = in_proj_w; out = w1t; R = 1024; C = 4096; rel = bx; gx = 128; }
  else if (bx < 4288) { in = x_proj_w; out = w3t; R = 2048; C = 96; rel = bx - 4096; gx = 3; }
  else if (bx < 4416) { in = dt_proj_w; out = w4t; R = 64; C = 2048; rel = bx - 4288; gx = 64; }
  else { in = out_proj_w; out = w5t; R = 2048; C = 1024; rel = bx - 4416; gx = 32; }
  const int c0 = (rel % gx) * 32, r0 = (rel / gx) * 32;

  __shared__ float tile[32][33];
  for (int y = ty; y < 32; y += 8) tile[y][tx] = in[(size_t)(r0 + y) * C + c0 + tx];
  __syncthreads();
  for (int y = ty; y < 32; y += 8) out[(size_t)(c0 + y) * R + r0 + tx] = f2bf(tile[tx][y]);
}

// depthwise causal conv (4 taps) + silu -> bf16 u only
__global__ void conv_silu_kernel(const float* __restrict__ xin, const float* __restrict__ cw,
                                 const float* __restrict__ cb, unsigned short* __restrict__ ub) {
  const int id = blockIdx.x * 256 + threadIdx.x;  // over 2048*2048
  const int t = id >> 11;
  const int d = id & (DINNER - 1);
  float acc = cb[d];
#pragma unroll
  for (int j = 0; j < 4; j++) {
    int tt = t - 3 + j;
    if (tt >= 0) acc += xin[(size_t)tt * DINNER + d] * cw[j * DINNER + d];
  }
  float s = acc / (1.f + __expf(-acc));  // silu
  ub[id] = f2bf(s);
}

// ---------------- bf16 MFMA GEMM: C[M,N] = A[M,K] @ Bt[N,K]^T ----------------
// BMxBN tile (64 or 128 each), BK=64 double-buffered LDS, post-barrier
// prefetch, XOR bank swizzle on 16B k-chunks. 4 waves in 2x2, wave tile
// (BM/2)x(BN/2).
// EPI: 0 = store fp32 +bias, 3 = split-K partial store (z-indexed),
//      4 = G1 dual: col<DINNER -> fp32 C (stride DINNER); else silu->bf16 C2,
//      5 = softplus(+bias) -> bf16 C2 (stride N).
template <int EPI, int BM, int BN>
__global__ void gemm_bf16(const unsigned short* __restrict__ A,
                          const unsigned short* __restrict__ Bt, float* __restrict__ C,
                          unsigned short* __restrict__ C2, const float* __restrict__ bias, int M,
                          int N, int K, int KS) {
  constexpr int MI = BM / 32, NJ = BN / 32;
  __shared__ __align__(16) unsigned short lA[2][BM * 64];
  __shared__ __align__(16) unsigned short lB[2][BN * 64];
  const int tid = threadIdx.x;
  const int w = tid >> 6;
  const int lane = tid & 63;
  const int m0 = blockIdx.x * BM;
  const int n0 = blockIdx.y * BN;
  const int kbase = blockIdx.z * KS;
  const int lr = lane >> 3;                  // row within 8-row staging group
  const int srcoff = ((lane & 7) ^ lr) * 8;  // swizzled source chunk (elems)
  const int wm = (w & 1) * (BM / 2);
  const int wn = (w >> 1) * (BN / 2);
  const int ml = lane & 15;
  const int quad = lane >> 4;

  f32x4 acc[MI][NJ];
#pragma unroll
  for (int i = 0; i < MI; i++)
#pragma unroll
    for (int j = 0; j < NJ; j++) acc[i][j] = (f32x4){0.f, 0.f, 0.f, 0.f};

  const unsigned short* Ag = A + (size_t)m0 * K + kbase;
  const unsigned short* Bg = Bt + (size_t)n0 * K + kbase;

  const int niter = KS >> 6;
  auto stage = [&](int buf, int kk) {
#pragma unroll
    for (int c2 = 0; c2 < BM / 32; c2++) {
      const int row = w * (BM / 4) + c2 * 8 + lr;
      gload16(Ag + (size_t)row * K + kk + srcoff, &lA[buf][(w * (BM / 4) + c2 * 8) * 64]);
    }
#pragma unroll
    for (int c2 = 0; c2 < BN / 32; c2++) {
      const int row = w * (BN / 4) + c2 * 8 + lr;
      gload16(Bg + (size_t)row * K + kk + srcoff, &lB[buf][(w * (BN / 4) + c2 * 8) * 64]);
    }
  };

  stage(0, 0);
  for (int it = 0; it < niter; it++) {
    __syncthreads();
    if (it + 1 < niter) stage((it + 1) & 1, (it + 1) << 6);  // overlaps MFMA below
    const unsigned short* bufA = lA[it & 1];
    const unsigned short* bufB = lB[it & 1];
#pragma unroll
    for (int ks = 0; ks < 2; ks++) {
      short8 af[MI], bfr[NJ];
#pragma unroll
      for (int i = 0; i < MI; i++) {
        const int row = wm + i * 16 + ml;
        af[i] = *(const short8*)&bufA[row * 64 + ((ks * 4 + quad) ^ (ml & 7)) * 8];
      }
#pragma unroll
      for (int j = 0; j < NJ; j++) {
        const int row = wn + j * 16 + ml;
        bfr[j] = *(const short8*)&bufB[row * 64 + ((ks * 4 + quad) ^ (ml & 7)) * 8];
      }
#pragma unroll
      for (int i = 0; i < MI; i++)
#pragma unroll
        for (int j = 0; j < NJ; j++)
          acc[i][j] = __builtin_amdgcn_mfma_f32_16x16x32_bf16(af[i], bfr[j], acc[i][j], 0, 0, 0);
    }
  }

  float* Cp = (EPI == 3) ? C + (size_t)blockIdx.z * M * N : C;
#pragma unroll
  for (int i = 0; i < MI; i++) {
#pragma unroll
    for (int j = 0; j < NJ; j++) {
      const int col = n0 + wn + j * 16 + ml;
      float bv = (EPI == 3) ? 0.f : (bias ? bias[col] : 0.f);
#pragma unroll
      for (int r = 0; r < 4; r++) {
        const int row = m0 + wm + i * 16 + quad * 4 + r;
        float v = acc[i][j][r] + bv;
        if (EPI == 0) {
          Cp[(size_t)row * N + col] = v;
        } else if (EPI == 3) {
          Cp[(size_t)row * N + col] = v;
        } else if (EPI == 4) {
          if (col < DINNER) {
            C[(size_t)row * DINNER + col] = v;
          } else {
            float s = v / (1.f + __expf(-v));
            C2[(size_t)row * DINNER + (col - DINNER)] = f2bf(s);
          }
        } else if (EPI == 5) {
          float sp = (v > 15.f) ? v : __logf(1.f + __expf(v));
          C2[(size_t)row * N + col] = f2bf(sp);
        }
      }
    }
  }
}

// sum 8 G3 partials -> dbc fp32; also emit dt slice (cols<64) as bf16
__global__ void reduce_dbc_kernel(const float* __restrict__ part, float* __restrict__ dbc,
                                  unsigned short* __restrict__ dtb) {
  const int id = blockIdx.x * 256 + threadIdx.x;  // 2048*128
  float s = 0.f;
#pragma unroll
  for (int z = 0; z < 8; z++) s += part[(size_t)z * (L_SEQ * NPROJ_PAD) + id];
  dbc[id] = s;
  const int col = id & 127;
  if (col < 64) dtb[(id >> 7) * 64 + col] = f2bf(s);
}

// ---------------- selective scan (chunked 2-pass, bf16 streams) ----------------

__global__ void scan1_kernel(const unsigned short* __restrict__ db,
                             const unsigned short* __restrict__ ub,
                             const float* __restrict__ dbc, const float* __restrict__ A_log,
                             unsigned short* __restrict__ P, unsigned short* __restrict__ Hz) {
  __shared__ float Bs[TCH][NSTATE];
  const int d = blockIdx.x * 256 + threadIdx.x;
  const int c = blockIdx.y;
  for (int idx = threadIdx.x; idx < TCH * NSTATE; idx += 256) {
    int t = idx >> 4, n = idx & 15;
    Bs[t][n] = dbc[(size_t)(c * TCH + t) * NPROJ_PAD + DTRANK + n];
  }
  float Ad[16], h[16], p[16];
#pragma unroll
  for (int n = 0; n < 16; n++) {
    Ad[n] = -__expf(A_log[d * 16 + n]);
    h[n] = 0.f;
    p[n] = 1.f;
  }
  __syncthreads();
#pragma unroll
  for (int t = 0; t < TCH; t++) {
    const int tt = c * TCH + t;
    float dl = bf2f(db[(size_t)tt * DINNER + d]);
    float uu = bf2f(ub[(size_t)tt * DINNER + d]);
    float du = dl * uu;
#pragma unroll
    for (int n = 0; n < 16; n++) {
      float dA = __expf(dl * Ad[n]);
      p[n] *= dA;
      h[n] = dA * h[n] + du * Bs[t][n];
    }
  }
#pragma unroll
  for (int n = 0; n < 16; n++) {
    P[(size_t)(c * 16 + n) * DINNER + d] = f2bf(p[n]);
    Hz[(size_t)(c * 16 + n) * DINNER + d] = f2bf(h[n]);
  }
}

__global__ void scan_carry_kernel(const unsigned short* __restrict__ P,
                                  const unsigned short* __restrict__ Hz,
                                  unsigned short* __restrict__ H0) {
  const int id = blockIdx.x * 256 + threadIdx.x;  // 16*2048 (n,d) pairs
  float h = 0.f;
#pragma unroll 8
  for (int c = 0; c < NCH; c++) {
    H0[c * (NSTATE * DINNER) + id] = f2bf(h);
    h = bf2f(P[c * (NSTATE * DINNER) + id]) * h + bf2f(Hz[c * (NSTATE * DINNER) + id]);
  }
}

__global__ void scan2_kernel(const unsigned short* __restrict__ db,
                             const unsigned short* __restrict__ ub,
                             const float* __restrict__ dbc, const float* __restrict__ A_log,
                             const float* __restrict__ Dv, const unsigned short* __restrict__ rsil,
                             const unsigned short* __restrict__ H0,
                             unsigned short* __restrict__ ygb) {
  __shared__ float Bs[TCH][NSTATE];
  __shared__ float Cs[TCH][NSTATE];
  const int d = blockIdx.x * 256 + threadIdx.x;
  const int c = blockIdx.y;
  for (int idx = threadIdx.x; idx < TCH * 2 * NSTATE; idx += 256) {
    int t = idx >> 5, q = idx & 31;
    float v = dbc[(size_t)(c * TCH + t) * NPROJ_PAD + DTRANK + q];
    if (q < 16) Bs[t][q] = v;
    else Cs[t][q - 16] = v;
  }
  float Ad[16], h[16];
#pragma unroll
  for (int n = 0; n < 16; n++) {
    Ad[n] = -__expf(A_log[d * 16 + n]);
    h[n] = bf2f(H0[(size_t)(c * 16 + n) * DINNER + d]);
  }
  const float Dd = Dv[d];
  __syncthreads();
#pragma unroll
  for (int t = 0; t < TCH; t++) {
    const int tt = c * TCH + t;
    float dl = bf2f(db[(size_t)tt * DINNER + d]);
    float uu = bf2f(ub[(size_t)tt * DINNER + d]);
    float rs = bf2f(rsil[(size_t)tt * DINNER + d]);  // silu(res) precomputed in G1
    float du = dl * uu;
    float y0 = 0.f, y1 = 0.f;
#pragma unroll
    for (int n = 0; n < 16; n++) {
      float dA = __expf(dl * Ad[n]);
      h[n] = dA * h[n] + du * Bs[t][n];
      if (n & 1) y1 += h[n] * Cs[t][n];
      else y0 += h[n] * Cs[t][n];
    }
    float yg = (y0 + y1 + uu * Dd) * rs;
    ygb[(size_t)tt * DINNER + d] = f2bf(yg);
  }
}

// ---------------- launch ----------------

extern "C" void kernel_launch(void* const* d_in, const int* in_sizes, int n_in, void* d_out,
                              int out_size, void* d_ws, size_t ws_size, hipStream_t stream) {
  const float* x = (const float*)d_in[0];
  const float* in_proj_w = (const float*)d_in[1];
  const float* in_proj_b = (const float*)d_in[2];
  const float* conv_w = (const float*)d_in[3];
  const float* conv_b = (const float*)d_in[4];
  const float* x_proj_w = (const float*)d_in[5];
  const float* dt_proj_w = (const float*)d_in[6];
  const float* dt_proj_b = (const float*)d_in[7];
  const float* A_log = (const float*)d_in[8];
  const float* Dvec = (const float*)d_in[9];
  const float* out_proj_w = (const float*)d_in[10];
  const float* out_proj_b = (const float*)d_in[11];
  float* out = (float*)d_out;
  char* ws = (char*)d_ws;
  (void)in_sizes; (void)n_in; (void)out_size; (void)ws_size;

  // workspace layout (MiB offsets), total ~98 MiB
  const size_t MB = 1048576;
  const size_t XB = 0;               // 2048x1024 bf16   4
  const size_t W1T = 4 * MB;         // 4096x1024 bf16   8
  const size_t XIN = 12 * MB;        // 2048x2048 fp32  16
  const size_t RSIL = 28 * MB;       // 2048x2048 bf16   8  (silu(res))
  const size_t UB = 36 * MB;         // 2048x2048 bf16   8
  const size_t W3T = 44 * MB;        // 128x2048 bf16  0.5
  const size_t DBC = W3T + 524288;   // 2048x128 fp32    1
  const size_t DTB = DBC + MB;       // 2048x64 bf16  0.25
  const size_t W4T = DTB + 262144;   // 2048x64 bf16  0.25
  const size_t DELTA = 46 * MB;      // 2048x2048 bf16   8
  const size_t YGB = 54 * MB;        // 2048x2048 bf16   8
  const size_t W5T = 62 * MB;        // 1024x2048 bf16   4
  const size_t G3P = 66 * MB;        // 8 x 1 MiB partials
  const size_t PB = 74 * MB;         // 128x16x2048 bf16 8
  const size_t HZB = 82 * MB;        // 8
  const size_t H0B = 90 * MB;        // 8

  // one prep kernel: 4 transposes + cast x + zero w3t pad
  prep_kernel<<<8544, dim3(32, 8), 0, stream>>>(
      in_proj_w, x_proj_w, dt_proj_w, out_proj_w, x, (unsigned short*)(ws + W1T),
      (unsigned short*)(ws + W3T), (unsigned short*)(ws + W4T), (unsigned short*)(ws + W5T),
      (unsigned short*)(ws + XB));

  // G1: [xin | silu(res)] = x @ in_proj_w + b   (M=2048,N=4096,K=1024)
  gemm_bf16<4, 128, 128><<<dim3(16, 32, 1), 256, 0, stream>>>(
      (const unsigned short*)(ws + XB), (const unsigned short*)(ws + W1T), (float*)(ws + XIN),
      (unsigned short*)(ws + RSIL), in_proj_b, 2048, 4096, 1024, 1024);

  // conv + silu -> u bf16
  conv_silu_kernel<<<(L_SEQ * DINNER) / 256, 256, 0, stream>>>(
      (const float*)(ws + XIN), conv_w, conv_b, (unsigned short*)(ws + UB));

  // G3: dbc partials (M=2048,N=128,K=2048, split-K=8, 64-row tiles)
  gemm_bf16<3, 64, 128><<<dim3(32, 1, 8), 256, 0, stream>>>(
      (const unsigned short*)(ws + UB), (const unsigned short*)(ws + W3T), (float*)(ws + G3P),
      nullptr, nullptr, 2048, NPROJ_PAD, 2048, 256);
  reduce_dbc_kernel<<<(L_SEQ * NPROJ_PAD) / 256, 256, 0, stream>>>(
      (const float*)(ws + G3P), (float*)(ws + DBC), (unsigned short*)(ws + DTB));

  // G5: delta = softplus(dt @ dt_proj_w + b) -> bf16  (M=2048,N=2048,K=64)
  gemm_bf16<5, 128, 128><<<dim3(16, 16, 1), 256, 0, stream>>>(
      (const unsigned short*)(ws + DTB), (const unsigned short*)(ws + W4T), nullptr,
      (unsigned short*)(ws + DELTA), dt_proj_b, 2048, 2048, 64, 64);

  // selective scan (128 chunks x 16 steps)
  const dim3 sgrid(DINNER / 256, NCH);
  scan1_kernel<<<sgrid, 256, 0, stream>>>(
      (const unsigned short*)(ws + DELTA), (const unsigned short*)(ws + UB),
      (const float*)(ws + DBC), A_log, (unsigned short*)(ws + PB), (unsigned short*)(ws + HZB));
  scan_carry_kernel<<<(NSTATE * DINNER) / 256, 256, 0, stream>>>(
      (const unsigned short*)(ws + PB), (const unsigned short*)(ws + HZB),
      (unsigned short*)(ws + H0B));
  scan2_kernel<<<sgrid, 256, 0, stream>>>(
      (const unsigned short*)(ws + DELTA), (const unsigned short*)(ws + UB),
      (const float*)(ws + DBC), A_log, Dvec, (const unsigned short*)(ws + RSIL),
      (const unsigned short*)(ws + H0B), (unsigned short*)(ws + YGB));

  // G2: out = yg @ out_proj_w + b  (M=2048,N=1024,K=2048, 64x64 tiles, direct)
  gemm_bf16<0, 64, 64><<<dim3(32, 16, 1), 256, 0, stream>>>(
      (const unsigned short*)(ws + YGB), (const unsigned short*)(ws + W5T), out, nullptr,
      out_proj_b, 2048, 1024, 2048, 2048);
}